// Round 5
// baseline (700.040 us; speedup 1.0000x reference)
//
#include <hip/hip_runtime.h>
#include <hip/hip_bf16.h>
#include <stdint.h>

#define T_TOK 8192
#define DDIM 1024
#define NEXP 8
#define IMOE 1024
#define ISH 4096
#define BK 64
#define PADTOT 17408  // 16384 pairs + 8*128 max padding

typedef __attribute__((ext_vector_type(8))) short short8;
typedef __attribute__((ext_vector_type(8))) __bf16 bf16x8;
typedef __attribute__((ext_vector_type(4))) float floatx4;

// round-to-nearest-even fp32 -> bf16 bits
__device__ __forceinline__ unsigned short f2bf(float f) {
  union { float f; unsigned u; } v; v.f = f;
  unsigned r = v.u + 0x7fffu + ((v.u >> 16) & 1u);
  return (unsigned short)(r >> 16);
}

__device__ __forceinline__ floatx4 mfma16(short8 a, short8 b, floatx4 c) {
  return __builtin_amdgcn_mfma_f32_16x16x32_bf16(
      __builtin_bit_cast(bf16x8, a), __builtin_bit_cast(bf16x8, b), c, 0, 0, 0);
}

// async global->LDS, 16B per lane; LDS base must be wave-uniform (global addr IS per-lane)
__device__ __forceinline__ void gload16(const void* g, void* l) {
  __builtin_amdgcn_global_load_lds((const __attribute__((address_space(1))) void*)g,
                                   (__attribute__((address_space(3))) void*)l, 16, 0, 0);
}

// N-strip XCD swizzle: XCD x owns n-blocks [x*gn/8, (x+1)*gn/8); within a strip
// m varies FASTEST, so the B n-panel (small: 0.25-2 MB) stays L2-resident per
// XCD while the large shared A operand streams through L3 in the same sequence
// on all 8 XCDs. (R4's m-slab grouping was backwards: it streamed all of B
// through each XCD's L2 -> FETCH 94->112 MB. This one targets FETCH ~= ideal.)
// Bijective for gn%8==0 (all four GEMM grids).
__device__ __forceinline__ void xcd_swz(int id, int gm, int gn, int& m, int& n) {
  int xcd = id & 7;
  int local = id >> 3;          // [0, gm*gn/8)
  m = local % gm;               // m fastest within the strip
  n = xcd * (gn >> 3) + local / gm;
}

// XOR swizzle: LDS 16B-block b of row r holds global block (b ^ (r&7)).
// Breaks the 16-way bank-group conflict of the BK=64 row stride (128B == 32 banks).

// ---------------- conversion kernels ----------------

__global__ void k_cast(const float* __restrict__ src, unsigned short* __restrict__ dst, int n) {
  int i = (blockIdx.x * blockDim.x + threadIdx.x) * 4;
  if (i < n) {
    float4 v = *(const float4*)(src + i);
    ushort4 o;
    o.x = f2bf(v.x); o.y = f2bf(v.y); o.z = f2bf(v.z); o.w = f2bf(v.w);
    *(ushort4*)(dst + i) = o;
  }
}

// src [batch][R][C] f32 -> dst [batch][C][R] bf16  (B^T layout for GEMM)
__global__ void k_transpose_cast(const float* __restrict__ src, unsigned short* __restrict__ dst,
                                 int R, int C) {
  __shared__ float tile[32][33];
  int b = blockIdx.z;
  int c0 = blockIdx.x * 32, r0 = blockIdx.y * 32;
  const float* s = src + (size_t)b * R * C;
  unsigned short* d = dst + (size_t)b * R * C;
  int tx = threadIdx.x, ty = threadIdx.y;  // 32 x 8
#pragma unroll
  for (int j = 0; j < 32; j += 8)
    tile[ty + j][tx] = s[(size_t)(r0 + ty + j) * C + c0 + tx];
  __syncthreads();
#pragma unroll
  for (int j = 0; j < 32; j += 8)
    d[(size_t)(c0 + ty + j) * R + r0 + tx] = f2bf(tile[tx][ty + j]);
}

// ---------------- router (no global atomics) ----------------

__global__ void k_router(const float* __restrict__ x, const float* __restrict__ gw,
                         const float* __restrict__ sgw, float* __restrict__ logits_out,
                         int* __restrict__ topi, float* __restrict__ topw,
                         float* __restrict__ sgate) {
  int wave = threadIdx.x >> 6;
  int lane = threadIdx.x & 63;
  int t = blockIdx.x * 4 + wave;
  const float* xr = x + (size_t)t * DDIM;
  float acc[9];
#pragma unroll
  for (int j = 0; j < 9; j++) acc[j] = 0.f;
  for (int d = lane; d < DDIM; d += 64) {
    float xv = xr[d];
    const float* g = gw + d * 8;
    float4 g0 = *(const float4*)g;
    float4 g1 = *(const float4*)(g + 4);
    acc[0] += xv * g0.x; acc[1] += xv * g0.y; acc[2] += xv * g0.z; acc[3] += xv * g0.w;
    acc[4] += xv * g1.x; acc[5] += xv * g1.y; acc[6] += xv * g1.z; acc[7] += xv * g1.w;
    acc[8] += xv * sgw[d];
  }
#pragma unroll
  for (int off = 32; off > 0; off >>= 1) {
#pragma unroll
    for (int j = 0; j < 9; j++) acc[j] += __shfl_xor(acc[j], off);
  }
  if (lane == 0) {
#pragma unroll
    for (int j = 0; j < 8; j++) logits_out[t * 8 + j] = acc[j];
    int i0 = 0;
#pragma unroll
    for (int j = 1; j < 8; j++) if (acc[j] > acc[i0]) i0 = j;
    int i1 = -1;
#pragma unroll
    for (int j = 0; j < 8; j++) {
      if (j == i0) continue;
      if (i1 < 0 || acc[j] > acc[i1]) i1 = j;
    }
    float e1 = expf(acc[i1] - acc[i0]);  // e0 = 1
    float inv = 1.f / (1.f + e1);
    topi[t * 2] = i0; topi[t * 2 + 1] = i1;
    topw[t * 2] = inv; topw[t * 2 + 1] = e1 * inv;
    sgate[t] = 1.f / (1.f + expf(-acc[8]));
  }
}

// Counting sort pass 1: per-block expert histogram (LDS atomics only).
__global__ void k_hist(const int* __restrict__ topi, int* __restrict__ blockhist) {
  __shared__ int h[NEXP];
  if (threadIdx.x < NEXP) h[threadIdx.x] = 0;
  __syncthreads();
  int i = blockIdx.x * 256 + threadIdx.x;  // pair index
  atomicAdd(&h[topi[i]], 1);
  __syncthreads();
  if (threadIdx.x < NEXP) blockhist[blockIdx.x * NEXP + threadIdx.x] = h[threadIdx.x];
}

// Pass 2: padded segment offsets (multiples of 128) + per-block bases + real counts.
__global__ void k_offsets(const int* __restrict__ blockhist, int* __restrict__ pseg,
                          int* __restrict__ rcnt, int* __restrict__ blockbase) {
  if (threadIdx.x == 0) {
    int tot[NEXP];
#pragma unroll
    for (int e = 0; e < NEXP; e++) tot[e] = 0;
    for (int b = 0; b < 64; b++)
      for (int e = 0; e < NEXP; e++) {
        blockbase[b * NEXP + e] = tot[e];
        tot[e] += blockhist[b * NEXP + e];
      }
    int s = 0;
    for (int e = 0; e < NEXP; e++) {
      rcnt[e] = tot[e];
      pseg[e] = s;
      s += (tot[e] + 127) & ~127;  // pad each segment to 128
    }
    pseg[NEXP] = s;
    for (int b = 0; b < 64; b++)
      for (int e = 0; e < NEXP; e++) blockbase[b * NEXP + e] += pseg[e];
  }
}

// Pass 3: scatter with per-block LDS cursors (no global atomics).
__global__ void k_scatter(const int* __restrict__ topi, const float* __restrict__ topw,
                          const int* __restrict__ blockbase,
                          int* __restrict__ ptok, float* __restrict__ pw) {
  __shared__ int cur[NEXP];
  if (threadIdx.x < NEXP) cur[threadIdx.x] = blockbase[blockIdx.x * NEXP + threadIdx.x];
  __syncthreads();
  int i = blockIdx.x * 256 + threadIdx.x;  // pair index
  int e = topi[i];
  int pos = atomicAdd(&cur[e], 1);
  ptok[pos] = i >> 1;
  pw[pos] = topw[i];
}

// ---------------- GEMM kernels (MFMA bf16 16x16x32, XOR-swizzled LDS) ----------------
// 32 KB LDS/block, VGPR<=128 -> 4 blocks/CU at __launch_bounds__(256,4).
// Fused gate/up + SiLU, shared expert: C tile 128(M) x 64(N), dual-B accs.
__global__ __launch_bounds__(256, 4) void k_gu_shared(
    const unsigned short* __restrict__ Xb,   // [8192][1024]
    const unsigned short* __restrict__ BgT,  // [4096][1024]
    const unsigned short* __restrict__ BuT,  // [4096][1024]
    unsigned short* __restrict__ H)          // [8192][4096]
{
  int bm, bn;
  xcd_swz(blockIdx.x, 64, 64, bm, bn);
  const int tm0 = bm * 128;
  const int tn0 = bn * 64;

  __shared__ __align__(16) unsigned short As[128 * BK];
  __shared__ __align__(16) unsigned short Bgs[64 * BK];
  __shared__ __align__(16) unsigned short Bus[64 * BK];

  const int tid = threadIdx.x;
  const int wave = tid >> 6, lane = tid & 63;
  const int wm = wave & 1, wn = wave >> 1;
  const int quad = lane >> 4, l16 = lane & 15;
  const int srow = lane >> 3;                        // 8 lanes per 64-elem row
  const int scol = ((lane & 7) ^ srow) * 8;          // swizzled global col block

  floatx4 accg[4][2] = {};
  floatx4 accu[4][2] = {};

  for (int k0 = 0; k0 < DDIM; k0 += BK) {
#pragma unroll
    for (int s = 0; s < 4; s++) {
      int rb = (wave * 4 + s) * 8;
      gload16(Xb + (size_t)(tm0 + rb + srow) * DDIM + k0 + scol, As + rb * BK);
    }
#pragma unroll
    for (int s = 0; s < 2; s++) {
      int rb = (wave * 2 + s) * 8;
      gload16(BgT + (size_t)(tn0 + rb + srow) * DDIM + k0 + scol, Bgs + rb * BK);
      gload16(BuT + (size_t)(tn0 + rb + srow) * DDIM + k0 + scol, Bus + rb * BK);
    }
    __syncthreads();
#pragma unroll
    for (int ks = 0; ks < BK; ks += 32) {
      short8 af[4], bg[2], bu[2];
#pragma unroll
      for (int f = 0; f < 4; f++) {
        int r = wm * 64 + f * 16 + l16;
        af[f] = *(const short8*)(As + r * BK + ((((ks >> 3) + quad) ^ (r & 7)) << 3));
      }
#pragma unroll
      for (int f = 0; f < 2; f++) {
        int r = wn * 32 + f * 16 + l16;
        int off = r * BK + ((((ks >> 3) + quad) ^ (r & 7)) << 3);
        bg[f] = *(const short8*)(Bgs + off);
        bu[f] = *(const short8*)(Bus + off);
      }
#pragma unroll
      for (int fm = 0; fm < 4; fm++)
#pragma unroll
        for (int fn = 0; fn < 2; fn++) {
          accg[fm][fn] = mfma16(af[fm], bg[fn], accg[fm][fn]);
          accu[fm][fn] = mfma16(af[fm], bu[fn], accu[fm][fn]);
        }
    }
    __syncthreads();
  }
#pragma unroll
  for (int fm = 0; fm < 4; fm++)
#pragma unroll
    for (int reg = 0; reg < 4; reg++) {
      int r = tm0 + wm * 64 + fm * 16 + quad * 4 + reg;
#pragma unroll
      for (int fn = 0; fn < 2; fn++) {
        int c = tn0 + wn * 32 + fn * 16 + l16;
        float g = accg[fm][fn][reg];
        float u = accu[fm][fn][reg];
        float h = (g / (1.f + __expf(-g))) * u;
        H[(size_t)r * ISH + c] = f2bf(h);
      }
    }
}

// Fused gate/up + SiLU for routed experts — A gathered on the fly from xb via
// per-lane ptok indirection (global side of global_load_lds is per-lane).
// Pad slots read row 0 (clamped garbage ptok); their Hp rows are garbage but
// are masked at the down_expert C-write, so never observed.
__global__ __launch_bounds__(256, 4) void k_gu_expert(
    const unsigned short* __restrict__ Xb,   // [8192][1024]
    const unsigned short* __restrict__ EgT,  // [E][1024][1024]
    const unsigned short* __restrict__ EuT,
    const int* __restrict__ pseg,
    const int* __restrict__ ptok,
    unsigned short* __restrict__ Hp)         // [PADTOT][1024] by pair slot
{
  int bm, bn;
  xcd_swz(blockIdx.x, PADTOT / 128, 16, bm, bn);
  const int m0 = bm * 128;
  if (m0 >= pseg[NEXP]) return;
  int e = 0;
#pragma unroll
  for (int j = 1; j < NEXP; j++) if (m0 >= pseg[j]) e = j;

  __shared__ __align__(16) unsigned short As[128 * BK];
  __shared__ __align__(16) unsigned short Bgs[64 * BK];
  __shared__ __align__(16) unsigned short Bus[64 * BK];

  const int tn0 = bn * 64;
  const int tid = threadIdx.x;
  const int wave = tid >> 6, lane = tid & 63;
  const int wm = wave & 1, wn = wave >> 1;
  const int quad = lane >> 4, l16 = lane & 15;
  const int srow = lane >> 3;
  const int scol = ((lane & 7) ^ srow) * 8;

  const unsigned short* Bg = EgT + (size_t)e * IMOE * DDIM;
  const unsigned short* Bu = EuT + (size_t)e * IMOE * DDIM;

  // indirect A staging pointers (4 parts of 32 rows each)
  const unsigned short* ArowP[4];
#pragma unroll
  for (int s = 0; s < 4; s++) {
    int tok = ptok[m0 + (wave * 4 + s) * 8 + srow];
    if (tok < 0 || tok >= T_TOK) tok = 0;  // pad slots: ptok is garbage
    ArowP[s] = Xb + (size_t)tok * DDIM + scol;
  }

  floatx4 accg[4][2] = {};
  floatx4 accu[4][2] = {};

  for (int k0 = 0; k0 < DDIM; k0 += BK) {
#pragma unroll
    for (int s = 0; s < 4; s++) {
      int rb = (wave * 4 + s) * 8;
      gload16(ArowP[s] + k0, As + rb * BK);
    }
#pragma unroll
    for (int s = 0; s < 2; s++) {
      int rb = (wave * 2 + s) * 8;
      gload16(Bg + (size_t)(tn0 + rb + srow) * DDIM + k0 + scol, Bgs + rb * BK);
      gload16(Bu + (size_t)(tn0 + rb + srow) * DDIM + k0 + scol, Bus + rb * BK);
    }
    __syncthreads();
#pragma unroll
    for (int ks = 0; ks < BK; ks += 32) {
      short8 af[4], bg[2], bu[2];
#pragma unroll
      for (int f = 0; f < 4; f++) {
        int r = wm * 64 + f * 16 + l16;
        af[f] = *(const short8*)(As + r * BK + ((((ks >> 3) + quad) ^ (r & 7)) << 3));
      }
#pragma unroll
      for (int f = 0; f < 2; f++) {
        int r = wn * 32 + f * 16 + l16;
        int off = r * BK + ((((ks >> 3) + quad) ^ (r & 7)) << 3);
        bg[f] = *(const short8*)(Bgs + off);
        bu[f] = *(const short8*)(Bus + off);
      }
#pragma unroll
      for (int fm = 0; fm < 4; fm++)
#pragma unroll
        for (int fn = 0; fn < 2; fn++) {
          accg[fm][fn] = mfma16(af[fm], bg[fn], accg[fm][fn]);
          accu[fm][fn] = mfma16(af[fm], bu[fn], accu[fm][fn]);
        }
    }
    __syncthreads();
  }
#pragma unroll
  for (int fm = 0; fm < 4; fm++)
#pragma unroll
    for (int reg = 0; reg < 4; reg++) {
      int r = m0 + wm * 64 + fm * 16 + quad * 4 + reg;
#pragma unroll
      for (int fn = 0; fn < 2; fn++) {
        int c = tn0 + wn * 32 + fn * 16 + l16;
        float g = accg[fm][fn][reg];
        float u = accu[fm][fn][reg];
        Hp[(size_t)r * IMOE + c] = f2bf((g / (1.f + __expf(-g))) * u);
      }
    }
}

// Shared-expert down proj: out = sigmoid_gate[t] * (Hsh @ sd). Writes full out.
__global__ __launch_bounds__(256, 4) void k_down_shared(
    const unsigned short* __restrict__ Hsh,  // [8192][4096]
    const unsigned short* __restrict__ SdT,  // [1024][4096]
    const float* __restrict__ sgate,
    float* __restrict__ out)                 // [8192][1024]
{
  __shared__ __align__(16) unsigned short As[128 * BK];
  __shared__ __align__(16) unsigned short Bs[128 * BK];

  int bm, bn;
  xcd_swz(blockIdx.x, 64, 8, bm, bn);
  const int tm0 = bm * 128;
  const int tn0 = bn * 128;
  const int tid = threadIdx.x;
  const int wave = tid >> 6, lane = tid & 63;
  const int wm = wave & 1, wn = wave >> 1;
  const int quad = lane >> 4, l16 = lane & 15;
  const int srow = lane >> 3;
  const int scol = ((lane & 7) ^ srow) * 8;

  floatx4 acc[4][4] = {};

  for (int k0 = 0; k0 < ISH; k0 += BK) {
#pragma unroll
    for (int s = 0; s < 4; s++) {
      int rb = (wave * 4 + s) * 8;
      gload16(Hsh + (size_t)(tm0 + rb + srow) * ISH + k0 + scol, As + rb * BK);
      gload16(SdT + (size_t)(tn0 + rb + srow) * ISH + k0 + scol, Bs + rb * BK);
    }
    __syncthreads();
#pragma unroll
    for (int ks = 0; ks < BK; ks += 32) {
      short8 af[4], bfr[4];
#pragma unroll
      for (int f = 0; f < 4; f++) {
        int ra = wm * 64 + f * 16 + l16;
        int rb2 = wn * 64 + f * 16 + l16;
        af[f] = *(const short8*)(As + ra * BK + ((((ks >> 3) + quad) ^ (ra & 7)) << 3));
        bfr[f] = *(const short8*)(Bs + rb2 * BK + ((((ks >> 3) + quad) ^ (rb2 & 7)) << 3));
      }
#pragma unroll
      for (int fm = 0; fm < 4; fm++)
#pragma unroll
        for (int fn = 0; fn < 4; fn++)
          acc[fm][fn] = mfma16(af[fm], bfr[fn], acc[fm][fn]);
    }
    __syncthreads();
  }
#pragma unroll
  for (int fm = 0; fm < 4; fm++)
#pragma unroll
    for (int reg = 0; reg < 4; reg++) {
      int r = tm0 + wm * 64 + fm * 16 + quad * 4 + reg;
      float gt = sgate[r];
#pragma unroll
      for (int fn = 0; fn < 4; fn++) {
        int c = tn0 + wn * 64 + fn * 16 + l16;
        out[(size_t)r * DDIM + c] = gt * acc[fm][fn][reg];
      }
    }
}

// Expert down proj: out[tok] += w_pair * (Hp @ ed[e]) via atomics. Sequential A.
__global__ __launch_bounds__(256, 4) void k_down_expert(
    const unsigned short* __restrict__ Hp,   // [PADTOT][1024]
    const unsigned short* __restrict__ EdT,  // [E][1024][1024]
    const int* __restrict__ pseg,
    const int* __restrict__ rcnt,
    const int* __restrict__ ptok,
    const float* __restrict__ pw,
    float* __restrict__ out)
{
  int bm, bn;
  xcd_swz(blockIdx.x, PADTOT / 128, 8, bm, bn);
  const int m0 = bm * 128;
  if (m0 >= pseg[NEXP]) return;
  int e = 0;
#pragma unroll
  for (int j = 1; j < NEXP; j++) if (m0 >= pseg[j]) e = j;
  const int sbase = pseg[e];
  const int cnt = rcnt[e];

  __shared__ __align__(16) unsigned short As[128 * BK];
  __shared__ __align__(16) unsigned short Bs[128 * BK];

  const int tn0 = bn * 128;
  const int tid = threadIdx.x;
  const int wave = tid >> 6, lane = tid & 63;
  const int wm = wave & 1, wn = wave >> 1;
  const int quad = lane >> 4, l16 = lane & 15;
  const int srow = lane >> 3;
  const int scol = ((lane & 7) ^ srow) * 8;

  const unsigned short* B = EdT + (size_t)e * IMOE * DDIM;

  floatx4 acc[4][4] = {};

  for (int k0 = 0; k0 < IMOE; k0 += BK) {
#pragma unroll
    for (int s = 0; s < 4; s++) {
      int rb = (wave * 4 + s) * 8;
      gload16(Hp + (size_t)(m0 + rb + srow) * IMOE + k0 + scol, As + rb * BK);
      gload16(B + (size_t)(tn0 + rb + srow) * IMOE + k0 + scol, Bs + rb * BK);
    }
    __syncthreads();
#pragma unroll
    for (int ks = 0; ks < BK; ks += 32) {
      short8 af[4], bfr[4];
#pragma unroll
      for (int f = 0; f < 4; f++) {
        int ra = wm * 64 + f * 16 + l16;
        int rb2 = wn * 64 + f * 16 + l16;
        af[f] = *(const short8*)(As + ra * BK + ((((ks >> 3) + quad) ^ (ra & 7)) << 3));
        bfr[f] = *(const short8*)(Bs + rb2 * BK + ((((ks >> 3) + quad) ^ (rb2 & 7)) << 3));
      }
#pragma unroll
      for (int fm = 0; fm < 4; fm++)
#pragma unroll
        for (int fn = 0; fn < 4; fn++)
          acc[fm][fn] = mfma16(af[fm], bfr[fn], acc[fm][fn]);
    }
    __syncthreads();
  }
#pragma unroll
  for (int fm = 0; fm < 4; fm++)
#pragma unroll
    for (int reg = 0; reg < 4; reg++) {
      int grow = m0 + wm * 64 + fm * 16 + quad * 4 + reg;
      if (grow - sbase < cnt) {
        int t = ptok[grow];
        float w = pw[grow];
#pragma unroll
        for (int fn = 0; fn < 4; fn++) {
          int c = tn0 + wn * 64 + fn * 16 + l16;
          atomicAdd(&out[(size_t)t * DDIM + c], w * acc[fm][fn][reg]);
        }
      }
    }
}

// ---------------- launch ----------------

extern "C" void kernel_launch(void* const* d_in, const int* in_sizes, int n_in,
                              void* d_out, int out_size, void* d_ws, size_t ws_size,
                              hipStream_t stream) {
  const float* x   = (const float*)d_in[0];
  const float* gw  = (const float*)d_in[1];
  const float* eg  = (const float*)d_in[2];
  const float* eu  = (const float*)d_in[3];
  const float* ed  = (const float*)d_in[4];
  const float* sg  = (const float*)d_in[5];
  const float* su  = (const float*)d_in[6];
  const float* sd  = (const float*)d_in[7];
  const float* sgw = (const float*)d_in[8];

  float* out    = (float*)d_out;                 // [8192][1024]
  float* logits = out + (size_t)T_TOK * DDIM;    // [8192][8]

  char* ws = (char*)d_ws;
  unsigned short* xb   = (unsigned short*)(ws + 0);            // 16 MB
  unsigned short* egT  = (unsigned short*)(ws + 16777216);     // 16 MB
  unsigned short* euT  = (unsigned short*)(ws + 33554432);     // 16 MB
  unsigned short* edT  = (unsigned short*)(ws + 50331648);     // 16 MB
  unsigned short* sgT  = (unsigned short*)(ws + 67108864);     // 8 MB
  unsigned short* suT  = (unsigned short*)(ws + 75497472);     // 8 MB
  unsigned short* sdT  = (unsigned short*)(ws + 83886080);     // 8 MB
  unsigned short* hsh  = (unsigned short*)(ws + 92274688);     // 64 MB
  unsigned short* hp   = (unsigned short*)(ws + 159383552);    // 35.65 MB
  int*   topi      = (int*)  (ws + 195035136);   // 16384 ints
  float* topw      = (float*)(ws + 195100672);   // 16384 floats
  float* sgate     = (float*)(ws + 195166208);   // 8192 floats
  int*   ptok      = (int*)  (ws + 195198976);   // PADTOT ints
  float* pw        = (float*)(ws + 195268608);   // PADTOT floats
  int*   blockhist = (int*)  (ws + 195338240);   // 64*8 ints
  int*   blockbase = (int*)  (ws + 195340288);   // 64*8 ints
  int*   pseg      = (int*)  (ws + 195342336);   // 9 ints
  int*   rcnt      = (int*)  (ws + 195342400);   // 8 ints

  k_cast<<<8192, 256, 0, stream>>>(x, xb, T_TOK * DDIM);
  k_transpose_cast<<<dim3(32, 32, 8), dim3(32, 8), 0, stream>>>(eg, egT, DDIM, IMOE);
  k_transpose_cast<<<dim3(32, 32, 8), dim3(32, 8), 0, stream>>>(eu, euT, DDIM, IMOE);
  k_transpose_cast<<<dim3(32, 32, 8), dim3(32, 8), 0, stream>>>(ed, edT, IMOE, DDIM);
  k_transpose_cast<<<dim3(128, 32, 1), dim3(32, 8), 0, stream>>>(sg, sgT, DDIM, ISH);
  k_transpose_cast<<<dim3(128, 32, 1), dim3(32, 8), 0, stream>>>(su, suT, DDIM, ISH);
  k_transpose_cast<<<dim3(32, 128, 1), dim3(32, 8), 0, stream>>>(sd, sdT, ISH, DDIM);

  k_router<<<T_TOK / 4, 256, 0, stream>>>(x, gw, sgw, logits, topi, topw, sgate);
  k_hist<<<64, 256, 0, stream>>>(topi, blockhist);
  k_offsets<<<1, 64, 0, stream>>>(blockhist, pseg, rcnt, blockbase);
  k_scatter<<<64, 256, 0, stream>>>(topi, topw, blockbase, ptok, pw);

  // Producer->consumer adjacency: hsh consumed right after production (L3-warm),
  // then hp likewise. down_shared's plain stores complete (stream order) before
  // down_expert's atomics accumulate on top.
  k_gu_shared<<<64 * 64, 256, 0, stream>>>(xb, sgT, suT, hsh);
  k_down_shared<<<64 * 8, 256, 0, stream>>>(hsh, sdT, sgate, out);
  k_gu_expert<<<(PADTOT / 128) * 16, 256, 0, stream>>>(xb, egT, euT, pseg, ptok, hp);
  k_down_expert<<<(PADTOT / 128) * 8, 256, 0, stream>>>(hp, edT, pseg, rcnt, ptok, pw, out);

  (void)in_sizes; (void)n_in; (void)out_size; (void)ws_size;
}

// Round 6
// 658.301 us; speedup vs baseline: 1.0634x; 1.0634x over previous
//
#include <hip/hip_runtime.h>
#include <hip/hip_bf16.h>
#include <stdint.h>

#define T_TOK 8192
#define DDIM 1024
#define NEXP 8
#define IMOE 1024
#define ISH 4096
#define BK 64
#define PADTOT 17408  // 16384 pairs + 8*128 max padding

typedef __attribute__((ext_vector_type(8))) short short8;
typedef __attribute__((ext_vector_type(8))) __bf16 bf16x8;
typedef __attribute__((ext_vector_type(4))) float floatx4;

// round-to-nearest-even fp32 -> bf16 bits
__device__ __forceinline__ unsigned short f2bf(float f) {
  union { float f; unsigned u; } v; v.f = f;
  unsigned r = v.u + 0x7fffu + ((v.u >> 16) & 1u);
  return (unsigned short)(r >> 16);
}

__device__ __forceinline__ floatx4 mfma16(short8 a, short8 b, floatx4 c) {
  return __builtin_amdgcn_mfma_f32_16x16x32_bf16(
      __builtin_bit_cast(bf16x8, a), __builtin_bit_cast(bf16x8, b), c, 0, 0, 0);
}

// async global->LDS, 16B per lane; LDS base must be wave-uniform (global addr IS per-lane)
__device__ __forceinline__ void gload16(const void* g, void* l) {
  __builtin_amdgcn_global_load_lds((const __attribute__((address_space(1))) void*)g,
                                   (__attribute__((address_space(3))) void*)l, 16, 0, 0);
}

// Dispatch-order note (R0/R4/R5 measured): DEFAULT order with blockIdx.x = m
// (fastest) is the best config — consecutive blocks share the B n-panel, which
// keeps it L2-resident under the HW round-robin XCD assignment. Both explicit
// XCD swizzles tried made FETCH worse (m-slab: 94->112 MB; n-strip: ->498 MB).

// XOR swizzle: LDS 16B-block b of row r holds global block (b ^ (r&7)).
// Breaks the 16-way bank-group conflict of the BK=64 row stride (128B == 32 banks).

// ---------------- weight conversion kernels ----------------

// src [R][C] f32 -> dst [C][R] bf16, batched over z by pointer select.
__device__ __forceinline__ void tr_cast_body(const float* __restrict__ s,
                                             unsigned short* __restrict__ d, int R, int C) {
  __shared__ float tile[32][33];
  int c0 = blockIdx.x * 32, r0 = blockIdx.y * 32;
  int tx = threadIdx.x, ty = threadIdx.y;  // 32 x 8
#pragma unroll
  for (int j = 0; j < 32; j += 8)
    tile[ty + j][tx] = s[(size_t)(r0 + ty + j) * C + c0 + tx];
  __syncthreads();
#pragma unroll
  for (int j = 0; j < 32; j += 8)
    d[(size_t)(c0 + ty + j) * R + r0 + tx] = f2bf(tile[tx][ty + j]);
}

// experts: eg/eu/ed, all 8 x [1024][1024]; z = sel*8 + b
__global__ void k_tr_experts(const float* __restrict__ eg, const float* __restrict__ eu,
                             const float* __restrict__ ed, unsigned short* __restrict__ egT,
                             unsigned short* __restrict__ euT, unsigned short* __restrict__ edT) {
  int z = blockIdx.z, sel = z >> 3, b = z & 7;
  const float* s = (sel == 0 ? eg : sel == 1 ? eu : ed) + (size_t)b * 1024 * 1024;
  unsigned short* d = (sel == 0 ? egT : sel == 1 ? euT : edT) + (size_t)b * 1024 * 1024;
  tr_cast_body(s, d, 1024, 1024);
}

// shared gate/up: [1024][4096] x2
__global__ void k_tr_su(const float* __restrict__ sg, const float* __restrict__ su,
                        unsigned short* __restrict__ sgT, unsigned short* __restrict__ suT) {
  if (blockIdx.z == 0) tr_cast_body(sg, sgT, DDIM, ISH);
  else                 tr_cast_body(su, suT, DDIM, ISH);
}

// shared down: [4096][1024]
__global__ void k_tr_sd(const float* __restrict__ sd, unsigned short* __restrict__ sdT) {
  tr_cast_body(sd, sdT, ISH, DDIM);
}

// ---------------- router (fused X f32->bf16 cast; no global atomics) ----------------

__global__ void k_router(const float* __restrict__ x, const float* __restrict__ gw,
                         const float* __restrict__ sgw, float* __restrict__ logits_out,
                         int* __restrict__ topi, float* __restrict__ topw,
                         float* __restrict__ sgate, unsigned short* __restrict__ xb) {
  int wave = threadIdx.x >> 6;
  int lane = threadIdx.x & 63;
  int t = blockIdx.x * 4 + wave;
  const float* xr = x + (size_t)t * DDIM;
  unsigned short* xbr = xb + (size_t)t * DDIM;
  float acc[9];
#pragma unroll
  for (int j = 0; j < 9; j++) acc[j] = 0.f;
  for (int d = lane; d < DDIM; d += 64) {
    float xv = xr[d];
    xbr[d] = f2bf(xv);  // fused cast (contiguous 128B per wave-iter)
    const float* g = gw + d * 8;
    float4 g0 = *(const float4*)g;
    float4 g1 = *(const float4*)(g + 4);
    acc[0] += xv * g0.x; acc[1] += xv * g0.y; acc[2] += xv * g0.z; acc[3] += xv * g0.w;
    acc[4] += xv * g1.x; acc[5] += xv * g1.y; acc[6] += xv * g1.z; acc[7] += xv * g1.w;
    acc[8] += xv * sgw[d];
  }
#pragma unroll
  for (int off = 32; off > 0; off >>= 1) {
#pragma unroll
    for (int j = 0; j < 9; j++) acc[j] += __shfl_xor(acc[j], off);
  }
  if (lane == 0) {
#pragma unroll
    for (int j = 0; j < 8; j++) logits_out[t * 8 + j] = acc[j];
    int i0 = 0;
#pragma unroll
    for (int j = 1; j < 8; j++) if (acc[j] > acc[i0]) i0 = j;
    int i1 = -1;
#pragma unroll
    for (int j = 0; j < 8; j++) {
      if (j == i0) continue;
      if (i1 < 0 || acc[j] > acc[i1]) i1 = j;
    }
    float e1 = expf(acc[i1] - acc[i0]);  // e0 = 1
    float inv = 1.f / (1.f + e1);
    topi[t * 2] = i0; topi[t * 2 + 1] = i1;
    topw[t * 2] = inv; topw[t * 2 + 1] = e1 * inv;
    sgate[t] = 1.f / (1.f + expf(-acc[8]));
  }
}

// Counting sort pass 1: per-block expert histogram (LDS atomics only).
__global__ void k_hist(const int* __restrict__ topi, int* __restrict__ blockhist) {
  __shared__ int h[NEXP];
  if (threadIdx.x < NEXP) h[threadIdx.x] = 0;
  __syncthreads();
  int i = blockIdx.x * 256 + threadIdx.x;  // pair index
  atomicAdd(&h[topi[i]], 1);
  __syncthreads();
  if (threadIdx.x < NEXP) blockhist[blockIdx.x * NEXP + threadIdx.x] = h[threadIdx.x];
}

// Pass 2: padded segment offsets (multiples of 128) + per-block bases + real counts.
__global__ void k_offsets(const int* __restrict__ blockhist, int* __restrict__ pseg,
                          int* __restrict__ rcnt, int* __restrict__ blockbase) {
  if (threadIdx.x == 0) {
    int tot[NEXP];
#pragma unroll
    for (int e = 0; e < NEXP; e++) tot[e] = 0;
    for (int b = 0; b < 64; b++)
      for (int e = 0; e < NEXP; e++) {
        blockbase[b * NEXP + e] = tot[e];
        tot[e] += blockhist[b * NEXP + e];
      }
    int s = 0;
    for (int e = 0; e < NEXP; e++) {
      rcnt[e] = tot[e];
      pseg[e] = s;
      s += (tot[e] + 127) & ~127;  // pad each segment to 128
    }
    pseg[NEXP] = s;
    for (int b = 0; b < 64; b++)
      for (int e = 0; e < NEXP; e++) blockbase[b * NEXP + e] += pseg[e];
  }
}

// Pass 3: scatter with per-block LDS cursors (no global atomics).
__global__ void k_scatter(const int* __restrict__ topi, const float* __restrict__ topw,
                          const int* __restrict__ blockbase,
                          int* __restrict__ ptok, float* __restrict__ pw) {
  __shared__ int cur[NEXP];
  if (threadIdx.x < NEXP) cur[threadIdx.x] = blockbase[blockIdx.x * NEXP + threadIdx.x];
  __syncthreads();
  int i = blockIdx.x * 256 + threadIdx.x;  // pair index
  int e = topi[i];
  int pos = atomicAdd(&cur[e], 1);
  ptok[pos] = i >> 1;
  pw[pos] = topw[i];
}

// ---------------- GEMM kernels (MFMA bf16 16x16x32, XOR-swizzled LDS) ----------------
// All use 128(M) x 64(N) tiles, 4 waves, 4 blocks/CU — the measured-best regime
// (MfmaUtil ~51% at 4/CU vs ~2/CU for 128x128 down tiles previously).

// Fused gate/up + SiLU, shared expert: dual-B accs.
__global__ __launch_bounds__(256, 4) void k_gu_shared(
    const unsigned short* __restrict__ Xb,   // [8192][1024]
    const unsigned short* __restrict__ BgT,  // [4096][1024]
    const unsigned short* __restrict__ BuT,  // [4096][1024]
    unsigned short* __restrict__ H)          // [8192][4096]
{
  const int tm0 = blockIdx.x * 128;
  const int tn0 = blockIdx.y * 64;

  __shared__ __align__(16) unsigned short As[128 * BK];
  __shared__ __align__(16) unsigned short Bgs[64 * BK];
  __shared__ __align__(16) unsigned short Bus[64 * BK];

  const int tid = threadIdx.x;
  const int wave = tid >> 6, lane = tid & 63;
  const int wm = wave & 1, wn = wave >> 1;
  const int quad = lane >> 4, l16 = lane & 15;
  const int srow = lane >> 3;                        // 8 lanes per 64-elem row
  const int scol = ((lane & 7) ^ srow) * 8;          // swizzled global col block

  floatx4 accg[4][2] = {};
  floatx4 accu[4][2] = {};

  for (int k0 = 0; k0 < DDIM; k0 += BK) {
#pragma unroll
    for (int s = 0; s < 4; s++) {
      int rb = (wave * 4 + s) * 8;
      gload16(Xb + (size_t)(tm0 + rb + srow) * DDIM + k0 + scol, As + rb * BK);
    }
#pragma unroll
    for (int s = 0; s < 2; s++) {
      int rb = (wave * 2 + s) * 8;
      gload16(BgT + (size_t)(tn0 + rb + srow) * DDIM + k0 + scol, Bgs + rb * BK);
      gload16(BuT + (size_t)(tn0 + rb + srow) * DDIM + k0 + scol, Bus + rb * BK);
    }
    __syncthreads();
#pragma unroll
    for (int ks = 0; ks < BK; ks += 32) {
      short8 af[4], bg[2], bu[2];
#pragma unroll
      for (int f = 0; f < 4; f++) {
        int r = wm * 64 + f * 16 + l16;
        af[f] = *(const short8*)(As + r * BK + ((((ks >> 3) + quad) ^ (r & 7)) << 3));
      }
#pragma unroll
      for (int f = 0; f < 2; f++) {
        int r = wn * 32 + f * 16 + l16;
        int off = r * BK + ((((ks >> 3) + quad) ^ (r & 7)) << 3);
        bg[f] = *(const short8*)(Bgs + off);
        bu[f] = *(const short8*)(Bus + off);
      }
#pragma unroll
      for (int fm = 0; fm < 4; fm++)
#pragma unroll
        for (int fn = 0; fn < 2; fn++) {
          accg[fm][fn] = mfma16(af[fm], bg[fn], accg[fm][fn]);
          accu[fm][fn] = mfma16(af[fm], bu[fn], accu[fm][fn]);
        }
    }
    __syncthreads();
  }
#pragma unroll
  for (int fm = 0; fm < 4; fm++)
#pragma unroll
    for (int reg = 0; reg < 4; reg++) {
      int r = tm0 + wm * 64 + fm * 16 + quad * 4 + reg;
#pragma unroll
      for (int fn = 0; fn < 2; fn++) {
        int c = tn0 + wn * 32 + fn * 16 + l16;
        float g = accg[fm][fn][reg];
        float u = accu[fm][fn][reg];
        float h = (g / (1.f + __expf(-g))) * u;
        H[(size_t)r * ISH + c] = f2bf(h);
      }
    }
}

// Fused gate/up + SiLU for routed experts — A gathered on the fly from xb via
// per-lane ptok indirection (global side of global_load_lds is per-lane).
// Pad slots read row 0 (clamped garbage ptok); their Hp rows are garbage but
// are masked at the down_expert C-write, so never observed.
__global__ __launch_bounds__(256, 4) void k_gu_expert(
    const unsigned short* __restrict__ Xb,   // [8192][1024]
    const unsigned short* __restrict__ EgT,  // [E][1024][1024]
    const unsigned short* __restrict__ EuT,
    const int* __restrict__ pseg,
    const int* __restrict__ ptok,
    unsigned short* __restrict__ Hp)         // [PADTOT][1024] by pair slot
{
  const int m0 = blockIdx.x * 128;
  if (m0 >= pseg[NEXP]) return;
  int e = 0;
#pragma unroll
  for (int j = 1; j < NEXP; j++) if (m0 >= pseg[j]) e = j;

  __shared__ __align__(16) unsigned short As[128 * BK];
  __shared__ __align__(16) unsigned short Bgs[64 * BK];
  __shared__ __align__(16) unsigned short Bus[64 * BK];

  const int tn0 = blockIdx.y * 64;
  const int tid = threadIdx.x;
  const int wave = tid >> 6, lane = tid & 63;
  const int wm = wave & 1, wn = wave >> 1;
  const int quad = lane >> 4, l16 = lane & 15;
  const int srow = lane >> 3;
  const int scol = ((lane & 7) ^ srow) * 8;

  const unsigned short* Bg = EgT + (size_t)e * IMOE * DDIM;
  const unsigned short* Bu = EuT + (size_t)e * IMOE * DDIM;

  // indirect A staging pointers (4 parts of 32 rows each)
  const unsigned short* ArowP[4];
#pragma unroll
  for (int s = 0; s < 4; s++) {
    int tok = ptok[m0 + (wave * 4 + s) * 8 + srow];
    if (tok < 0 || tok >= T_TOK) tok = 0;  // pad slots: ptok is garbage
    ArowP[s] = Xb + (size_t)tok * DDIM + scol;
  }

  floatx4 accg[4][2] = {};
  floatx4 accu[4][2] = {};

  for (int k0 = 0; k0 < DDIM; k0 += BK) {
#pragma unroll
    for (int s = 0; s < 4; s++) {
      int rb = (wave * 4 + s) * 8;
      gload16(ArowP[s] + k0, As + rb * BK);
    }
#pragma unroll
    for (int s = 0; s < 2; s++) {
      int rb = (wave * 2 + s) * 8;
      gload16(Bg + (size_t)(tn0 + rb + srow) * DDIM + k0 + scol, Bgs + rb * BK);
      gload16(Bu + (size_t)(tn0 + rb + srow) * DDIM + k0 + scol, Bus + rb * BK);
    }
    __syncthreads();
#pragma unroll
    for (int ks = 0; ks < BK; ks += 32) {
      short8 af[4], bg[2], bu[2];
#pragma unroll
      for (int f = 0; f < 4; f++) {
        int r = wm * 64 + f * 16 + l16;
        af[f] = *(const short8*)(As + r * BK + ((((ks >> 3) + quad) ^ (r & 7)) << 3));
      }
#pragma unroll
      for (int f = 0; f < 2; f++) {
        int r = wn * 32 + f * 16 + l16;
        int off = r * BK + ((((ks >> 3) + quad) ^ (r & 7)) << 3);
        bg[f] = *(const short8*)(Bgs + off);
        bu[f] = *(const short8*)(Bus + off);
      }
#pragma unroll
      for (int fm = 0; fm < 4; fm++)
#pragma unroll
        for (int fn = 0; fn < 2; fn++) {
          accg[fm][fn] = mfma16(af[fm], bg[fn], accg[fm][fn]);
          accu[fm][fn] = mfma16(af[fm], bu[fn], accu[fm][fn]);
        }
    }
    __syncthreads();
  }
#pragma unroll
  for (int fm = 0; fm < 4; fm++)
#pragma unroll
    for (int reg = 0; reg < 4; reg++) {
      int r = m0 + wm * 64 + fm * 16 + quad * 4 + reg;
#pragma unroll
      for (int fn = 0; fn < 2; fn++) {
        int c = tn0 + wn * 32 + fn * 16 + l16;
        float g = accg[fm][fn][reg];
        float u = accu[fm][fn][reg];
        Hp[(size_t)r * IMOE + c] = f2bf((g / (1.f + __expf(-g))) * u);
      }
    }
}

// Shared-expert down proj: out = sigmoid_gate[t] * (Hsh @ sd). 128x64 tile.
__global__ __launch_bounds__(256, 4) void k_down_shared(
    const unsigned short* __restrict__ Hsh,  // [8192][4096]
    const unsigned short* __restrict__ SdT,  // [1024][4096]
    const float* __restrict__ sgate,
    float* __restrict__ out)                 // [8192][1024]
{
  __shared__ __align__(16) unsigned short As[128 * BK];
  __shared__ __align__(16) unsigned short Bs[64 * BK];

  const int tm0 = blockIdx.x * 128;
  const int tn0 = blockIdx.y * 64;
  const int tid = threadIdx.x;
  const int wave = tid >> 6, lane = tid & 63;
  const int wm = wave & 1, wn = wave >> 1;
  const int quad = lane >> 4, l16 = lane & 15;
  const int srow = lane >> 3;
  const int scol = ((lane & 7) ^ srow) * 8;

  floatx4 acc[4][2] = {};

  for (int k0 = 0; k0 < ISH; k0 += BK) {
#pragma unroll
    for (int s = 0; s < 4; s++) {
      int rb = (wave * 4 + s) * 8;
      gload16(Hsh + (size_t)(tm0 + rb + srow) * ISH + k0 + scol, As + rb * BK);
    }
#pragma unroll
    for (int s = 0; s < 2; s++) {
      int rb = (wave * 2 + s) * 8;
      gload16(SdT + (size_t)(tn0 + rb + srow) * ISH + k0 + scol, Bs + rb * BK);
    }
    __syncthreads();
#pragma unroll
    for (int ks = 0; ks < BK; ks += 32) {
      short8 af[4], bfr[2];
#pragma unroll
      for (int f = 0; f < 4; f++) {
        int r = wm * 64 + f * 16 + l16;
        af[f] = *(const short8*)(As + r * BK + ((((ks >> 3) + quad) ^ (r & 7)) << 3));
      }
#pragma unroll
      for (int f = 0; f < 2; f++) {
        int r = wn * 32 + f * 16 + l16;
        bfr[f] = *(const short8*)(Bs + r * BK + ((((ks >> 3) + quad) ^ (r & 7)) << 3));
      }
#pragma unroll
      for (int fm = 0; fm < 4; fm++)
#pragma unroll
        for (int fn = 0; fn < 2; fn++)
          acc[fm][fn] = mfma16(af[fm], bfr[fn], acc[fm][fn]);
    }
    __syncthreads();
  }
#pragma unroll
  for (int fm = 0; fm < 4; fm++)
#pragma unroll
    for (int reg = 0; reg < 4; reg++) {
      int r = tm0 + wm * 64 + fm * 16 + quad * 4 + reg;
      float gt = sgate[r];
#pragma unroll
      for (int fn = 0; fn < 2; fn++) {
        int c = tn0 + wn * 32 + fn * 16 + l16;
        out[(size_t)r * DDIM + c] = gt * acc[fm][fn][reg];
      }
    }
}

// Expert down proj: out[tok] += w_pair * (Hp @ ed[e]) via atomics. 128x64 tile.
__global__ __launch_bounds__(256, 4) void k_down_expert(
    const unsigned short* __restrict__ Hp,   // [PADTOT][1024]
    const unsigned short* __restrict__ EdT,  // [E][1024][1024]
    const int* __restrict__ pseg,
    const int* __restrict__ rcnt,
    const int* __restrict__ ptok,
    const float* __restrict__ pw,
    float* __restrict__ out)
{
  const int m0 = blockIdx.x * 128;
  if (m0 >= pseg[NEXP]) return;
  int e = 0;
#pragma unroll
  for (int j = 1; j < NEXP; j++) if (m0 >= pseg[j]) e = j;
  const int sbase = pseg[e];
  const int cnt = rcnt[e];

  __shared__ __align__(16) unsigned short As[128 * BK];
  __shared__ __align__(16) unsigned short Bs[64 * BK];

  const int tn0 = blockIdx.y * 64;
  const int tid = threadIdx.x;
  const int wave = tid >> 6, lane = tid & 63;
  const int wm = wave & 1, wn = wave >> 1;
  const int quad = lane >> 4, l16 = lane & 15;
  const int srow = lane >> 3;
  const int scol = ((lane & 7) ^ srow) * 8;

  const unsigned short* B = EdT + (size_t)e * IMOE * DDIM;

  floatx4 acc[4][2] = {};

  for (int k0 = 0; k0 < IMOE; k0 += BK) {
#pragma unroll
    for (int s = 0; s < 4; s++) {
      int rb = (wave * 4 + s) * 8;
      gload16(Hp + (size_t)(m0 + rb + srow) * IMOE + k0 + scol, As + rb * BK);
    }
#pragma unroll
    for (int s = 0; s < 2; s++) {
      int rb = (wave * 2 + s) * 8;
      gload16(B + (size_t)(tn0 + rb + srow) * IMOE + k0 + scol, Bs + rb * BK);
    }
    __syncthreads();
#pragma unroll
    for (int ks = 0; ks < BK; ks += 32) {
      short8 af[4], bfr[2];
#pragma unroll
      for (int f = 0; f < 4; f++) {
        int r = wm * 64 + f * 16 + l16;
        af[f] = *(const short8*)(As + r * BK + ((((ks >> 3) + quad) ^ (r & 7)) << 3));
      }
#pragma unroll
      for (int f = 0; f < 2; f++) {
        int r = wn * 32 + f * 16 + l16;
        bfr[f] = *(const short8*)(Bs + r * BK + ((((ks >> 3) + quad) ^ (r & 7)) << 3));
      }
#pragma unroll
      for (int fm = 0; fm < 4; fm++)
#pragma unroll
        for (int fn = 0; fn < 2; fn++)
          acc[fm][fn] = mfma16(af[fm], bfr[fn], acc[fm][fn]);
    }
    __syncthreads();
  }
#pragma unroll
  for (int fm = 0; fm < 4; fm++)
#pragma unroll
    for (int reg = 0; reg < 4; reg++) {
      int grow = m0 + wm * 64 + fm * 16 + quad * 4 + reg;
      if (grow - sbase < cnt) {
        int t = ptok[grow];
        float w = pw[grow];
#pragma unroll
        for (int fn = 0; fn < 2; fn++) {
          int c = tn0 + wn * 32 + fn * 16 + l16;
          atomicAdd(&out[(size_t)t * DDIM + c], w * acc[fm][fn][reg]);
        }
      }
    }
}

// ---------------- launch ----------------

extern "C" void kernel_launch(void* const* d_in, const int* in_sizes, int n_in,
                              void* d_out, int out_size, void* d_ws, size_t ws_size,
                              hipStream_t stream) {
  const float* x   = (const float*)d_in[0];
  const float* gw  = (const float*)d_in[1];
  const float* eg  = (const float*)d_in[2];
  const float* eu  = (const float*)d_in[3];
  const float* ed  = (const float*)d_in[4];
  const float* sg  = (const float*)d_in[5];
  const float* su  = (const float*)d_in[6];
  const float* sd  = (const float*)d_in[7];
  const float* sgw = (const float*)d_in[8];

  float* out    = (float*)d_out;                 // [8192][1024]
  float* logits = out + (size_t)T_TOK * DDIM;    // [8192][8]

  char* ws = (char*)d_ws;
  unsigned short* xb   = (unsigned short*)(ws + 0);            // 16 MB
  unsigned short* egT  = (unsigned short*)(ws + 16777216);     // 16 MB
  unsigned short* euT  = (unsigned short*)(ws + 33554432);     // 16 MB
  unsigned short* edT  = (unsigned short*)(ws + 50331648);     // 16 MB
  unsigned short* sgT  = (unsigned short*)(ws + 67108864);     // 8 MB
  unsigned short* suT  = (unsigned short*)(ws + 75497472);     // 8 MB
  unsigned short* sdT  = (unsigned short*)(ws + 83886080);     // 8 MB
  unsigned short* hsh  = (unsigned short*)(ws + 92274688);     // 64 MB
  unsigned short* hp   = (unsigned short*)(ws + 159383552);    // 35.65 MB
  int*   topi      = (int*)  (ws + 195035136);   // 16384 ints
  float* topw      = (float*)(ws + 195100672);   // 16384 floats
  float* sgate     = (float*)(ws + 195166208);   // 8192 floats
  int*   ptok      = (int*)  (ws + 195198976);   // PADTOT ints
  float* pw        = (float*)(ws + 195268608);   // PADTOT floats
  int*   blockhist = (int*)  (ws + 195338240);   // 64*8 ints
  int*   blockbase = (int*)  (ws + 195340288);   // 64*8 ints
  int*   pseg      = (int*)  (ws + 195342336);   // 9 ints
  int*   rcnt     = (int*)  (ws + 195342400);   // 8 ints

  k_router<<<T_TOK / 4, 256, 0, stream>>>(x, gw, sgw, logits, topi, topw, sgate, xb);
  k_tr_experts<<<dim3(32, 32, 24), dim3(32, 8), 0, stream>>>(eg, eu, ed, egT, euT, edT);
  k_tr_su<<<dim3(128, 32, 2), dim3(32, 8), 0, stream>>>(sg, su, sgT, suT);
  k_tr_sd<<<dim3(32, 128, 1), dim3(32, 8), 0, stream>>>(sd, sdT);

  k_hist<<<64, 256, 0, stream>>>(topi, blockhist);
  k_offsets<<<1, 64, 0, stream>>>(blockhist, pseg, rcnt, blockbase);
  k_scatter<<<64, 256, 0, stream>>>(topi, topw, blockbase, ptok, pw);

  // Producer->consumer adjacency; down_shared's plain stores complete (stream
  // order) before down_expert's atomics accumulate on top.
  k_gu_shared<<<dim3(64, 64), 256, 0, stream>>>(xb, sgT, suT, hsh);
  k_down_shared<<<dim3(64, 16), 256, 0, stream>>>(hsh, sdT, sgate, out);
  k_gu_expert<<<dim3(PADTOT / 128, 16), 256, 0, stream>>>(xb, egT, euT, pseg, ptok, hp);
  k_down_expert<<<dim3(PADTOT / 128, 16), 256, 0, stream>>>(hp, edT, pseg, rcnt, ptok, pw, out);

  (void)in_sizes; (void)n_in; (void)out_size; (void)ws_size;
}

// Round 8
// 617.849 us; speedup vs baseline: 1.1330x; 1.0655x over previous
//
#include <hip/hip_runtime.h>
#include <hip/hip_bf16.h>
#include <stdint.h>

#define T_TOK 8192
#define DDIM 1024
#define NEXP 8
#define IMOE 1024
#define ISH 4096
#define BK 64
#define PADTOT 17408  // 16384 pairs + 8*128 max padding

typedef __attribute__((ext_vector_type(8))) short short8;
typedef __attribute__((ext_vector_type(8))) __bf16 bf16x8;
typedef __attribute__((ext_vector_type(4))) float floatx4;

// round-to-nearest-even fp32 -> bf16 bits
__device__ __forceinline__ unsigned short f2bf(float f) {
  union { float f; unsigned u; } v; v.f = f;
  unsigned r = v.u + 0x7fffu + ((v.u >> 16) & 1u);
  return (unsigned short)(r >> 16);
}

__device__ __forceinline__ floatx4 mfma16(short8 a, short8 b, floatx4 c) {
  return __builtin_amdgcn_mfma_f32_16x16x32_bf16(
      __builtin_bit_cast(bf16x8, a), __builtin_bit_cast(bf16x8, b), c, 0, 0, 0);
}

// async global->LDS, 16B per lane; LDS base must be wave-uniform (global addr IS per-lane)
__device__ __forceinline__ void gload16(const void* g, void* l) {
  __builtin_amdgcn_global_load_lds((const __attribute__((address_space(1))) void*)g,
                                   (__attribute__((address_space(3))) void*)l, 16, 0, 0);
}

// Dispatch-order policy (R0/R4/R5/R6 measured):
//  - B working set > L2 (gu_shared 16MB, down_shared 8MB): DEFAULT order
//    (m fastest keeps the current B n-panel L2-resident). gu_shared: 130us/94MB.
//  - B working set <= L2 (expert kernels: 2-4MB/expert): m-slab swizzle — each
//    XCD takes all-n for an m-chunk, so the whole expert B stays L2-resident.
//  NOTE (R7 failure): swz_ms decodes BOTH m and n from a single 1-D block id —
//  the kernels using it MUST be launched with 1-D grids of gm*gn blocks.
__device__ __forceinline__ void swz_ms(int id, int gm, int gn, int& m, int& n) {
  int cpx = (gm * gn) >> 3;
  int wg = (id & 7) * cpx + (id >> 3);
  int g = wg >> 6, r = wg & 63;
  int gpr = gn >> 3;
  m = ((g / gpr) << 3) | (r >> 3);
  n = ((g % gpr) << 3) | (r & 7);
}

// XOR swizzle: LDS 16B-block b of row r holds global block (b ^ (r&7)).
// Breaks the 16-way bank-group conflict of the BK=64 row stride (128B == 32 banks).

// ---------------- weight conversion kernels ----------------

// src [R][C] f32 -> dst [C][R] bf16, batched over z by pointer select.
__device__ __forceinline__ void tr_cast_body(const float* __restrict__ s,
                                             unsigned short* __restrict__ d, int R, int C) {
  __shared__ float tile[32][33];
  int c0 = blockIdx.x * 32, r0 = blockIdx.y * 32;
  int tx = threadIdx.x, ty = threadIdx.y;  // 32 x 8
#pragma unroll
  for (int j = 0; j < 32; j += 8)
    tile[ty + j][tx] = s[(size_t)(r0 + ty + j) * C + c0 + tx];
  __syncthreads();
#pragma unroll
  for (int j = 0; j < 32; j += 8)
    d[(size_t)(c0 + ty + j) * R + r0 + tx] = f2bf(tile[tx][ty + j]);
}

// experts: eg/eu/ed, all 8 x [1024][1024]; z = sel*8 + b
__global__ void k_tr_experts(const float* __restrict__ eg, const float* __restrict__ eu,
                             const float* __restrict__ ed, unsigned short* __restrict__ egT,
                             unsigned short* __restrict__ euT, unsigned short* __restrict__ edT) {
  int z = blockIdx.z, sel = z >> 3, b = z & 7;
  const float* s = (sel == 0 ? eg : sel == 1 ? eu : ed) + (size_t)b * 1024 * 1024;
  unsigned short* d = (sel == 0 ? egT : sel == 1 ? euT : edT) + (size_t)b * 1024 * 1024;
  tr_cast_body(s, d, 1024, 1024);
}

// shared gate/up: [1024][4096] x2
__global__ void k_tr_su(const float* __restrict__ sg, const float* __restrict__ su,
                        unsigned short* __restrict__ sgT, unsigned short* __restrict__ suT) {
  if (blockIdx.z == 0) tr_cast_body(sg, sgT, DDIM, ISH);
  else                 tr_cast_body(su, suT, DDIM, ISH);
}

// shared down: [4096][1024]
__global__ void k_tr_sd(const float* __restrict__ sd, unsigned short* __restrict__ sdT) {
  tr_cast_body(sd, sdT, ISH, DDIM);
}

// ---------------- router (fused X f32->bf16 cast; no global atomics) ----------------

__global__ void k_router(const float* __restrict__ x, const float* __restrict__ gw,
                         const float* __restrict__ sgw, float* __restrict__ logits_out,
                         int* __restrict__ topi, float* __restrict__ topw,
                         float* __restrict__ sgate, unsigned short* __restrict__ xb) {
  int wave = threadIdx.x >> 6;
  int lane = threadIdx.x & 63;
  int t = blockIdx.x * 4 + wave;
  const float* xr = x + (size_t)t * DDIM;
  unsigned short* xbr = xb + (size_t)t * DDIM;
  float acc[9];
#pragma unroll
  for (int j = 0; j < 9; j++) acc[j] = 0.f;
  for (int d = lane; d < DDIM; d += 64) {
    float xv = xr[d];
    xbr[d] = f2bf(xv);  // fused cast (contiguous 128B per wave-iter)
    const float* g = gw + d * 8;
    float4 g0 = *(const float4*)g;
    float4 g1 = *(const float4*)(g + 4);
    acc[0] += xv * g0.x; acc[1] += xv * g0.y; acc[2] += xv * g0.z; acc[3] += xv * g0.w;
    acc[4] += xv * g1.x; acc[5] += xv * g1.y; acc[6] += xv * g1.z; acc[7] += xv * g1.w;
    acc[8] += xv * sgw[d];
  }
#pragma unroll
  for (int off = 32; off > 0; off >>= 1) {
#pragma unroll
    for (int j = 0; j < 9; j++) acc[j] += __shfl_xor(acc[j], off);
  }
  if (lane == 0) {
#pragma unroll
    for (int j = 0; j < 8; j++) logits_out[t * 8 + j] = acc[j];
    int i0 = 0;
#pragma unroll
    for (int j = 1; j < 8; j++) if (acc[j] > acc[i0]) i0 = j;
    int i1 = -1;
#pragma unroll
    for (int j = 0; j < 8; j++) {
      if (j == i0) continue;
      if (i1 < 0 || acc[j] > acc[i1]) i1 = j;
    }
    float e1 = expf(acc[i1] - acc[i0]);  // e0 = 1
    float inv = 1.f / (1.f + e1);
    topi[t * 2] = i0; topi[t * 2 + 1] = i1;
    topw[t * 2] = inv; topw[t * 2 + 1] = e1 * inv;
    sgate[t] = 1.f / (1.f + expf(-acc[8]));
  }
}

// Counting sort pass 1: per-block expert histogram (LDS atomics only).
__global__ void k_hist(const int* __restrict__ topi, int* __restrict__ blockhist) {
  __shared__ int h[NEXP];
  if (threadIdx.x < NEXP) h[threadIdx.x] = 0;
  __syncthreads();
  int i = blockIdx.x * 256 + threadIdx.x;  // pair index
  atomicAdd(&h[topi[i]], 1);
  __syncthreads();
  if (threadIdx.x < NEXP) blockhist[blockIdx.x * NEXP + threadIdx.x] = h[threadIdx.x];
}

// Pass 2 (parallelized; was single-thread ~25us of serial global latency):
// stage hist in LDS, 8 parallel per-expert prefix scans, parallel writeback.
__global__ void k_offsets(const int* __restrict__ blockhist, int* __restrict__ pseg,
                          int* __restrict__ rcnt, int* __restrict__ blockbase) {
  __shared__ int h[64 * NEXP];
  __shared__ int tot[NEXP], ps[NEXP + 1];
  int t = threadIdx.x;  // 64 threads
#pragma unroll
  for (int j = 0; j < 8; j++) h[j * 64 + t] = blockhist[j * 64 + t];
  __syncthreads();
  if (t < NEXP) {
    int s = 0;
    for (int b = 0; b < 64; b++) {
      int v = h[b * NEXP + t];
      h[b * NEXP + t] = s;  // exclusive prefix within expert
      s += v;
    }
    tot[t] = s;
    rcnt[t] = s;
  }
  __syncthreads();
  if (t == 0) {
    int s = 0;
    for (int e = 0; e < NEXP; e++) { ps[e] = s; s += (tot[e] + 127) & ~127; }
    ps[NEXP] = s;
#pragma unroll
    for (int e = 0; e <= NEXP; e++) pseg[e] = ps[e];
  }
  __syncthreads();
#pragma unroll
  for (int j = 0; j < 8; j++) {
    int idx = j * 64 + t;  // idx = b*NEXP + e
    blockbase[idx] = h[idx] + ps[idx & 7];
  }
}

// Pass 3: scatter with per-block LDS cursors (no global atomics).
__global__ void k_scatter(const int* __restrict__ topi, const float* __restrict__ topw,
                          const int* __restrict__ blockbase,
                          int* __restrict__ ptok, float* __restrict__ pw) {
  __shared__ int cur[NEXP];
  if (threadIdx.x < NEXP) cur[threadIdx.x] = blockbase[blockIdx.x * NEXP + threadIdx.x];
  __syncthreads();
  int i = blockIdx.x * 256 + threadIdx.x;  // pair index
  int e = topi[i];
  int pos = atomicAdd(&cur[e], 1);
  ptok[pos] = i >> 1;
  pw[pos] = topw[i];
}

// ---------------- GEMM kernels (MFMA bf16 16x16x32, XOR-swizzled LDS) ----------------

// Fused gate/up + SiLU, shared expert: 128x64 tile, dual-B accs, DEFAULT order.
__global__ __launch_bounds__(256, 4) void k_gu_shared(
    const unsigned short* __restrict__ Xb,   // [8192][1024]
    const unsigned short* __restrict__ BgT,  // [4096][1024]
    const unsigned short* __restrict__ BuT,  // [4096][1024]
    unsigned short* __restrict__ H)          // [8192][4096]
{
  const int tm0 = blockIdx.x * 128;
  const int tn0 = blockIdx.y * 64;

  __shared__ __align__(16) unsigned short As[128 * BK];
  __shared__ __align__(16) unsigned short Bgs[64 * BK];
  __shared__ __align__(16) unsigned short Bus[64 * BK];

  const int tid = threadIdx.x;
  const int wave = tid >> 6, lane = tid & 63;
  const int wm = wave & 1, wn = wave >> 1;
  const int quad = lane >> 4, l16 = lane & 15;
  const int srow = lane >> 3;                        // 8 lanes per 64-elem row
  const int scol = ((lane & 7) ^ srow) * 8;          // swizzled global col block

  floatx4 accg[4][2] = {};
  floatx4 accu[4][2] = {};

  for (int k0 = 0; k0 < DDIM; k0 += BK) {
#pragma unroll
    for (int s = 0; s < 4; s++) {
      int rb = (wave * 4 + s) * 8;
      gload16(Xb + (size_t)(tm0 + rb + srow) * DDIM + k0 + scol, As + rb * BK);
    }
#pragma unroll
    for (int s = 0; s < 2; s++) {
      int rb = (wave * 2 + s) * 8;
      gload16(BgT + (size_t)(tn0 + rb + srow) * DDIM + k0 + scol, Bgs + rb * BK);
      gload16(BuT + (size_t)(tn0 + rb + srow) * DDIM + k0 + scol, Bus + rb * BK);
    }
    __syncthreads();
#pragma unroll
    for (int ks = 0; ks < BK; ks += 32) {
      short8 af[4], bg[2], bu[2];
#pragma unroll
      for (int f = 0; f < 4; f++) {
        int r = wm * 64 + f * 16 + l16;
        af[f] = *(const short8*)(As + r * BK + ((((ks >> 3) + quad) ^ (r & 7)) << 3));
      }
#pragma unroll
      for (int f = 0; f < 2; f++) {
        int r = wn * 32 + f * 16 + l16;
        int off = r * BK + ((((ks >> 3) + quad) ^ (r & 7)) << 3);
        bg[f] = *(const short8*)(Bgs + off);
        bu[f] = *(const short8*)(Bus + off);
      }
#pragma unroll
      for (int fm = 0; fm < 4; fm++)
#pragma unroll
        for (int fn = 0; fn < 2; fn++) {
          accg[fm][fn] = mfma16(af[fm], bg[fn], accg[fm][fn]);
          accu[fm][fn] = mfma16(af[fm], bu[fn], accu[fm][fn]);
        }
    }
    __syncthreads();
  }
#pragma unroll
  for (int fm = 0; fm < 4; fm++)
#pragma unroll
    for (int reg = 0; reg < 4; reg++) {
      int r = tm0 + wm * 64 + fm * 16 + quad * 4 + reg;
#pragma unroll
      for (int fn = 0; fn < 2; fn++) {
        int c = tn0 + wn * 32 + fn * 16 + l16;
        float g = accg[fm][fn][reg];
        float u = accu[fm][fn][reg];
        float h = (g / (1.f + __expf(-g))) * u;
        H[(size_t)r * ISH + c] = f2bf(h);
      }
    }
}

// Fused gate/up + SiLU for routed experts — A gathered on the fly from xb via
// per-lane ptok indirection. m-slab XCD swizzle (B 4MB/expert = L2-fit).
// MUST be launched 1-D with (PADTOT/128)*16 blocks.
__global__ __launch_bounds__(256, 4) void k_gu_expert(
    const unsigned short* __restrict__ Xb,   // [8192][1024]
    const unsigned short* __restrict__ EgT,  // [E][1024][1024]
    const unsigned short* __restrict__ EuT,
    const int* __restrict__ pseg,
    const int* __restrict__ ptok,
    unsigned short* __restrict__ Hp)         // [PADTOT][1024] by pair slot
{
  int bm, bn;
  swz_ms(blockIdx.x, PADTOT / 128, 16, bm, bn);
  const int m0 = bm * 128;
  if (m0 >= pseg[NEXP]) return;
  int e = 0;
#pragma unroll
  for (int j = 1; j < NEXP; j++) if (m0 >= pseg[j]) e = j;

  __shared__ __align__(16) unsigned short As[128 * BK];
  __shared__ __align__(16) unsigned short Bgs[64 * BK];
  __shared__ __align__(16) unsigned short Bus[64 * BK];

  const int tn0 = bn * 64;
  const int tid = threadIdx.x;
  const int wave = tid >> 6, lane = tid & 63;
  const int wm = wave & 1, wn = wave >> 1;
  const int quad = lane >> 4, l16 = lane & 15;
  const int srow = lane >> 3;
  const int scol = ((lane & 7) ^ srow) * 8;

  const unsigned short* Bg = EgT + (size_t)e * IMOE * DDIM;
  const unsigned short* Bu = EuT + (size_t)e * IMOE * DDIM;

  // indirect A staging pointers (4 parts of 32 rows each)
  const unsigned short* ArowP[4];
#pragma unroll
  for (int s = 0; s < 4; s++) {
    int tok = ptok[m0 + (wave * 4 + s) * 8 + srow];
    if (tok < 0 || tok >= T_TOK) tok = 0;  // pad slots: ptok is garbage
    ArowP[s] = Xb + (size_t)tok * DDIM + scol;
  }

  floatx4 accg[4][2] = {};
  floatx4 accu[4][2] = {};

  for (int k0 = 0; k0 < DDIM; k0 += BK) {
#pragma unroll
    for (int s = 0; s < 4; s++) {
      int rb = (wave * 4 + s) * 8;
      gload16(ArowP[s] + k0, As + rb * BK);
    }
#pragma unroll
    for (int s = 0; s < 2; s++) {
      int rb = (wave * 2 + s) * 8;
      gload16(Bg + (size_t)(tn0 + rb + srow) * DDIM + k0 + scol, Bgs + rb * BK);
      gload16(Bu + (size_t)(tn0 + rb + srow) * DDIM + k0 + scol, Bus + rb * BK);
    }
    __syncthreads();
#pragma unroll
    for (int ks = 0; ks < BK; ks += 32) {
      short8 af[4], bg[2], bu[2];
#pragma unroll
      for (int f = 0; f < 4; f++) {
        int r = wm * 64 + f * 16 + l16;
        af[f] = *(const short8*)(As + r * BK + ((((ks >> 3) + quad) ^ (r & 7)) << 3));
      }
#pragma unroll
      for (int f = 0; f < 2; f++) {
        int r = wn * 32 + f * 16 + l16;
        int off = r * BK + ((((ks >> 3) + quad) ^ (r & 7)) << 3);
        bg[f] = *(const short8*)(Bgs + off);
        bu[f] = *(const short8*)(Bus + off);
      }
#pragma unroll
      for (int fm = 0; fm < 4; fm++)
#pragma unroll
        for (int fn = 0; fn < 2; fn++) {
          accg[fm][fn] = mfma16(af[fm], bg[fn], accg[fm][fn]);
          accu[fm][fn] = mfma16(af[fm], bu[fn], accu[fm][fn]);
        }
    }
    __syncthreads();
  }
#pragma unroll
  for (int fm = 0; fm < 4; fm++)
#pragma unroll
    for (int reg = 0; reg < 4; reg++) {
      int r = m0 + wm * 64 + fm * 16 + quad * 4 + reg;
#pragma unroll
      for (int fn = 0; fn < 2; fn++) {
        int c = tn0 + wn * 32 + fn * 16 + l16;
        float g = accg[fm][fn][reg];
        float u = accu[fm][fn][reg];
        Hp[(size_t)r * IMOE + c] = f2bf((g / (1.f + __expf(-g))) * u);
      }
    }
}

// Shared-expert down proj: out = sigmoid_gate[t] * (Hsh @ sd). 128x128, DEFAULT.
__global__ __launch_bounds__(256, 4) void k_down_shared(
    const unsigned short* __restrict__ Hsh,  // [8192][4096]
    const unsigned short* __restrict__ SdT,  // [1024][4096]
    const float* __restrict__ sgate,
    float* __restrict__ out)                 // [8192][1024]
{
  __shared__ __align__(16) unsigned short As[128 * BK];
  __shared__ __align__(16) unsigned short Bs[128 * BK];

  const int tm0 = blockIdx.x * 128;
  const int tn0 = blockIdx.y * 128;
  const int tid = threadIdx.x;
  const int wave = tid >> 6, lane = tid & 63;
  const int wm = wave & 1, wn = wave >> 1;
  const int quad = lane >> 4, l16 = lane & 15;
  const int srow = lane >> 3;
  const int scol = ((lane & 7) ^ srow) * 8;

  floatx4 acc[4][4] = {};

  for (int k0 = 0; k0 < ISH; k0 += BK) {
#pragma unroll
    for (int s = 0; s < 4; s++) {
      int rb = (wave * 4 + s) * 8;
      gload16(Hsh + (size_t)(tm0 + rb + srow) * ISH + k0 + scol, As + rb * BK);
      gload16(SdT + (size_t)(tn0 + rb + srow) * ISH + k0 + scol, Bs + rb * BK);
    }
    __syncthreads();
#pragma unroll
    for (int ks = 0; ks < BK; ks += 32) {
      short8 af[4], bfr[4];
#pragma unroll
      for (int f = 0; f < 4; f++) {
        int ra = wm * 64 + f * 16 + l16;
        int rb2 = wn * 64 + f * 16 + l16;
        af[f] = *(const short8*)(As + ra * BK + ((((ks >> 3) + quad) ^ (ra & 7)) << 3));
        bfr[f] = *(const short8*)(Bs + rb2 * BK + ((((ks >> 3) + quad) ^ (rb2 & 7)) << 3));
      }
#pragma unroll
      for (int fm = 0; fm < 4; fm++)
#pragma unroll
        for (int fn = 0; fn < 4; fn++)
          acc[fm][fn] = mfma16(af[fm], bfr[fn], acc[fm][fn]);
    }
    __syncthreads();
  }
#pragma unroll
  for (int fm = 0; fm < 4; fm++)
#pragma unroll
    for (int reg = 0; reg < 4; reg++) {
      int r = tm0 + wm * 64 + fm * 16 + quad * 4 + reg;
      float gt = sgate[r];
#pragma unroll
      for (int fn = 0; fn < 4; fn++) {
        int c = tn0 + wn * 64 + fn * 16 + l16;
        out[(size_t)r * DDIM + c] = gt * acc[fm][fn][reg];
      }
    }
}

// Expert down proj: out[tok] += w_pair * (Hp @ ed[e]). 128x128, m-slab swizzle
// (B 2MB/expert = L2-fit). MUST be launched 1-D with (PADTOT/128)*8 blocks.
__global__ __launch_bounds__(256, 4) void k_down_expert(
    const unsigned short* __restrict__ Hp,   // [PADTOT][1024]
    const unsigned short* __restrict__ EdT,  // [E][1024][1024]
    const int* __restrict__ pseg,
    const int* __restrict__ rcnt,
    const int* __restrict__ ptok,
    const float* __restrict__ pw,
    float* __restrict__ out)
{
  int bm, bn;
  swz_ms(blockIdx.x, PADTOT / 128, 8, bm, bn);
  const int m0 = bm * 128;
  if (m0 >= pseg[NEXP]) return;
  int e = 0;
#pragma unroll
  for (int j = 1; j < NEXP; j++) if (m0 >= pseg[j]) e = j;
  const int sbase = pseg[e];
  const int cnt = rcnt[e];

  __shared__ __align__(16) unsigned short As[128 * BK];
  __shared__ __align__(16) unsigned short Bs[128 * BK];

  const int tn0 = bn * 128;
  const int tid = threadIdx.x;
  const int wave = tid >> 6, lane = tid & 63;
  const int wm = wave & 1, wn = wave >> 1;
  const int quad = lane >> 4, l16 = lane & 15;
  const int srow = lane >> 3;
  const int scol = ((lane & 7) ^ srow) * 8;

  const unsigned short* B = EdT + (size_t)e * IMOE * DDIM;

  floatx4 acc[4][4] = {};

  for (int k0 = 0; k0 < IMOE; k0 += BK) {
#pragma unroll
    for (int s = 0; s < 4; s++) {
      int rb = (wave * 4 + s) * 8;
      gload16(Hp + (size_t)(m0 + rb + srow) * IMOE + k0 + scol, As + rb * BK);
      gload16(B + (size_t)(tn0 + rb + srow) * IMOE + k0 + scol, Bs + rb * BK);
    }
    __syncthreads();
#pragma unroll
    for (int ks = 0; ks < BK; ks += 32) {
      short8 af[4], bfr[4];
#pragma unroll
      for (int f = 0; f < 4; f++) {
        int ra = wm * 64 + f * 16 + l16;
        int rb2 = wn * 64 + f * 16 + l16;
        af[f] = *(const short8*)(As + ra * BK + ((((ks >> 3) + quad) ^ (ra & 7)) << 3));
        bfr[f] = *(const short8*)(Bs + rb2 * BK + ((((ks >> 3) + quad) ^ (rb2 & 7)) << 3));
      }
#pragma unroll
      for (int fm = 0; fm < 4; fm++)
#pragma unroll
        for (int fn = 0; fn < 4; fn++)
          acc[fm][fn] = mfma16(af[fm], bfr[fn], acc[fm][fn]);
    }
    __syncthreads();
  }
#pragma unroll
  for (int fm = 0; fm < 4; fm++)
#pragma unroll
    for (int reg = 0; reg < 4; reg++) {
      int grow = m0 + wm * 64 + fm * 16 + quad * 4 + reg;
      if (grow - sbase < cnt) {
        int t = ptok[grow];
        float w = pw[grow];
#pragma unroll
        for (int fn = 0; fn < 4; fn++) {
          int c = tn0 + wn * 64 + fn * 16 + l16;
          atomicAdd(&out[(size_t)t * DDIM + c], w * acc[fm][fn][reg]);
        }
      }
    }
}

// ---------------- launch ----------------

extern "C" void kernel_launch(void* const* d_in, const int* in_sizes, int n_in,
                              void* d_out, int out_size, void* d_ws, size_t ws_size,
                              hipStream_t stream) {
  const float* x   = (const float*)d_in[0];
  const float* gw  = (const float*)d_in[1];
  const float* eg  = (const float*)d_in[2];
  const float* eu  = (const float*)d_in[3];
  const float* ed  = (const float*)d_in[4];
  const float* sg  = (const float*)d_in[5];
  const float* su  = (const float*)d_in[6];
  const float* sd  = (const float*)d_in[7];
  const float* sgw = (const float*)d_in[8];

  float* out    = (float*)d_out;                 // [8192][1024]
  float* logits = out + (size_t)T_TOK * DDIM;    // [8192][8]

  char* ws = (char*)d_ws;
  unsigned short* xb   = (unsigned short*)(ws + 0);            // 16 MB
  unsigned short* egT  = (unsigned short*)(ws + 16777216);     // 16 MB
  unsigned short* euT  = (unsigned short*)(ws + 33554432);     // 16 MB
  unsigned short* edT  = (unsigned short*)(ws + 50331648);     // 16 MB
  unsigned short* sgT  = (unsigned short*)(ws + 67108864);     // 8 MB
  unsigned short* suT  = (unsigned short*)(ws + 75497472);     // 8 MB
  unsigned short* sdT  = (unsigned short*)(ws + 83886080);     // 8 MB
  unsigned short* hsh  = (unsigned short*)(ws + 92274688);     // 64 MB
  unsigned short* hp   = (unsigned short*)(ws + 159383552);    // 35.65 MB
  int*   topi      = (int*)  (ws + 195035136);   // 16384 ints
  float* topw      = (float*)(ws + 195100672);   // 16384 floats
  float* sgate     = (float*)(ws + 195166208);   // 8192 floats
  int*   ptok      = (int*)  (ws + 195198976);   // PADTOT ints
  float* pw        = (float*)(ws + 195268608);   // PADTOT floats
  int*   blockhist = (int*)  (ws + 195338240);   // 64*8 ints
  int*   blockbase = (int*)  (ws + 195340288);   // 64*8 ints
  int*   pseg      = (int*)  (ws + 195342336);   // 9 ints
  int*   rcnt     = (int*)  (ws + 195342400);   // 8 ints

  k_router<<<T_TOK / 4, 256, 0, stream>>>(x, gw, sgw, logits, topi, topw, sgate, xb);
  k_tr_experts<<<dim3(32, 32, 24), dim3(32, 8), 0, stream>>>(eg, eu, ed, egT, euT, edT);
  k_tr_su<<<dim3(128, 32, 2), dim3(32, 8), 0, stream>>>(sg, su, sgT, suT);
  k_tr_sd<<<dim3(32, 128, 1), dim3(32, 8), 0, stream>>>(sd, sdT);

  k_hist<<<64, 256, 0, stream>>>(topi, blockhist);
  k_offsets<<<1, 64, 0, stream>>>(blockhist, pseg, rcnt, blockbase);
  k_scatter<<<64, 256, 0, stream>>>(topi, topw, blockbase, ptok, pw);

  // Producer->consumer adjacency; down_shared's plain stores complete (stream
  // order) before down_expert's atomics accumulate on top.
  // Expert kernels: 1-D grids — swz_ms decodes (m,n) from the single block id.
  k_gu_shared<<<dim3(64, 64), 256, 0, stream>>>(xb, sgT, suT, hsh);
  k_down_shared<<<dim3(64, 8), 256, 0, stream>>>(hsh, sdT, sgate, out);
  k_gu_expert<<<(PADTOT / 128) * 16, 256, 0, stream>>>(xb, egT, euT, pseg, ptok, hp);
  k_down_expert<<<(PADTOT / 128) * 8, 256, 0, stream>>>(hp, edT, pseg, rcnt, ptok, pw, out);

  (void)in_sizes; (void)n_in; (void)out_size; (void)ws_size;
}

// Round 9
// 615.263 us; speedup vs baseline: 1.1378x; 1.0042x over previous
//
#include <hip/hip_runtime.h>
#include <hip/hip_bf16.h>
#include <stdint.h>

#define T_TOK 8192
#define DDIM 1024
#define NEXP 8
#define IMOE 1024
#define ISH 4096
#define BK 64
#define PADTOT 17408  // 16384 pairs + 8*128 max padding

typedef __attribute__((ext_vector_type(8))) short short8;
typedef __attribute__((ext_vector_type(8))) __bf16 bf16x8;
typedef __attribute__((ext_vector_type(4))) float floatx4;

// round-to-nearest-even fp32 -> bf16 bits
__device__ __forceinline__ unsigned short f2bf(float f) {
  union { float f; unsigned u; } v; v.f = f;
  unsigned r = v.u + 0x7fffu + ((v.u >> 16) & 1u);
  return (unsigned short)(r >> 16);
}

__device__ __forceinline__ floatx4 mfma16(short8 a, short8 b, floatx4 c) {
  return __builtin_amdgcn_mfma_f32_16x16x32_bf16(
      __builtin_bit_cast(bf16x8, a), __builtin_bit_cast(bf16x8, b), c, 0, 0, 0);
}

// async global->LDS, 16B per lane; LDS base must be wave-uniform (global addr IS per-lane)
__device__ __forceinline__ void gload16(const void* g, void* l) {
  __builtin_amdgcn_global_load_lds((const __attribute__((address_space(1))) void*)g,
                                   (__attribute__((address_space(3))) void*)l, 16, 0, 0);
}

// Dispatch-order policy (R0/R4/R5/R6/R8 measured):
//  - B working set > L2 (gu_shared 16MB, down_shared 8MB): DEFAULT order
//    (m fastest keeps the current B n-panel L2-resident). gu_shared: 130us/94MB.
//  - B working set <= L2 (expert kernels: 2-4MB/expert): m-slab swizzle — each
//    XCD takes all-n for an m-chunk, so the whole expert B stays L2-resident.
//  NOTE (R7 failure): swz_ms decodes BOTH m and n from a single 1-D block id —
//  the kernels using it MUST be launched with 1-D grids of gm*gn blocks.
__device__ __forceinline__ void swz_ms(int id, int gm, int gn, int& m, int& n) {
  int cpx = (gm * gn) >> 3;
  int wg = (id & 7) * cpx + (id >> 3);
  int g = wg >> 6, r = wg & 63;
  int gpr = gn >> 3;
  m = ((g / gpr) << 3) | (r >> 3);
  n = ((g % gpr) << 3) | (r & 7);
}

// XOR swizzle: LDS 16B-block b of row r holds global block (b ^ (r&7)).
// Breaks the 16-way bank-group conflict of the BK=64 row stride (128B == 32 banks).

// ---------------- weight conversion kernels (vectorized, R9) ----------------
// 64x64 tile, 256 threads. float4 loads (16B/lane), LDS f32 [64][65] (pad-65:
// column reads are 2-way bank aliasing = free), ushort4 stores (8B/lane,
// 16 lanes = contiguous 128B). Replaces scalar 4B-load/2B-store version.

__device__ __forceinline__ void tr64_body(const float* __restrict__ s,
                                          unsigned short* __restrict__ d, int R, int C) {
  __shared__ float tile[64][65];
  const int c0 = blockIdx.x * 64, r0 = blockIdx.y * 64;
  const int t = threadIdx.x;  // 256
  const int lrow = t >> 4, lc4 = (t & 15) * 4;
#pragma unroll
  for (int j = 0; j < 4; j++) {
    int row = lrow + j * 16;
    float4 v = *(const float4*)(s + (size_t)(r0 + row) * C + c0 + lc4);
    tile[row][lc4 + 0] = v.x;
    tile[row][lc4 + 1] = v.y;
    tile[row][lc4 + 2] = v.z;
    tile[row][lc4 + 3] = v.w;
  }
  __syncthreads();
  const int rchunk = t & 15, oc0 = t >> 4;
#pragma unroll
  for (int j = 0; j < 4; j++) {
    int oc = oc0 + j * 16;
    ushort4 o;
    o.x = f2bf(tile[rchunk * 4 + 0][oc]);
    o.y = f2bf(tile[rchunk * 4 + 1][oc]);
    o.z = f2bf(tile[rchunk * 4 + 2][oc]);
    o.w = f2bf(tile[rchunk * 4 + 3][oc]);
    *(ushort4*)(d + (size_t)(c0 + oc) * R + r0 + rchunk * 4) = o;
  }
}

// experts: eg/eu/ed, all 8 x [1024][1024]; z = sel*8 + b
__global__ void k_tr_experts(const float* __restrict__ eg, const float* __restrict__ eu,
                             const float* __restrict__ ed, unsigned short* __restrict__ egT,
                             unsigned short* __restrict__ euT, unsigned short* __restrict__ edT) {
  int z = blockIdx.z, sel = z >> 3, b = z & 7;
  const float* s = (sel == 0 ? eg : sel == 1 ? eu : ed) + (size_t)b * 1024 * 1024;
  unsigned short* d = (sel == 0 ? egT : sel == 1 ? euT : edT) + (size_t)b * 1024 * 1024;
  tr64_body(s, d, 1024, 1024);
}

// shared gate/up: [1024][4096] x2
__global__ void k_tr_su(const float* __restrict__ sg, const float* __restrict__ su,
                        unsigned short* __restrict__ sgT, unsigned short* __restrict__ suT) {
  if (blockIdx.z == 0) tr64_body(sg, sgT, DDIM, ISH);
  else                 tr64_body(su, suT, DDIM, ISH);
}

// shared down: [4096][1024]
__global__ void k_tr_sd(const float* __restrict__ sd, unsigned short* __restrict__ sdT) {
  tr64_body(sd, sdT, ISH, DDIM);
}

// ---------------- router (fused X f32->bf16 cast; no global atomics) ----------------

__global__ void k_router(const float* __restrict__ x, const float* __restrict__ gw,
                         const float* __restrict__ sgw, float* __restrict__ logits_out,
                         int* __restrict__ topi, float* __restrict__ topw,
                         float* __restrict__ sgate, unsigned short* __restrict__ xb) {
  int wave = threadIdx.x >> 6;
  int lane = threadIdx.x & 63;
  int t = blockIdx.x * 4 + wave;
  const float* xr = x + (size_t)t * DDIM;
  unsigned short* xbr = xb + (size_t)t * DDIM;
  float acc[9];
#pragma unroll
  for (int j = 0; j < 9; j++) acc[j] = 0.f;
  for (int d = lane; d < DDIM; d += 64) {
    float xv = xr[d];
    xbr[d] = f2bf(xv);  // fused cast (contiguous 128B per wave-iter)
    const float* g = gw + d * 8;
    float4 g0 = *(const float4*)g;
    float4 g1 = *(const float4*)(g + 4);
    acc[0] += xv * g0.x; acc[1] += xv * g0.y; acc[2] += xv * g0.z; acc[3] += xv * g0.w;
    acc[4] += xv * g1.x; acc[5] += xv * g1.y; acc[6] += xv * g1.z; acc[7] += xv * g1.w;
    acc[8] += xv * sgw[d];
  }
#pragma unroll
  for (int off = 32; off > 0; off >>= 1) {
#pragma unroll
    for (int j = 0; j < 9; j++) acc[j] += __shfl_xor(acc[j], off);
  }
  if (lane == 0) {
#pragma unroll
    for (int j = 0; j < 8; j++) logits_out[t * 8 + j] = acc[j];
    int i0 = 0;
#pragma unroll
    for (int j = 1; j < 8; j++) if (acc[j] > acc[i0]) i0 = j;
    int i1 = -1;
#pragma unroll
    for (int j = 0; j < 8; j++) {
      if (j == i0) continue;
      if (i1 < 0 || acc[j] > acc[i1]) i1 = j;
    }
    float e1 = expf(acc[i1] - acc[i0]);  // e0 = 1
    float inv = 1.f / (1.f + e1);
    topi[t * 2] = i0; topi[t * 2 + 1] = i1;
    topw[t * 2] = inv; topw[t * 2 + 1] = e1 * inv;
    sgate[t] = 1.f / (1.f + expf(-acc[8]));
  }
}

// Counting sort pass 1: per-block expert histogram (LDS atomics only).
__global__ void k_hist(const int* __restrict__ topi, int* __restrict__ blockhist) {
  __shared__ int h[NEXP];
  if (threadIdx.x < NEXP) h[threadIdx.x] = 0;
  __syncthreads();
  int i = blockIdx.x * 256 + threadIdx.x;  // pair index
  atomicAdd(&h[topi[i]], 1);
  __syncthreads();
  if (threadIdx.x < NEXP) blockhist[blockIdx.x * NEXP + threadIdx.x] = h[threadIdx.x];
}

// Pass 2 (parallelized): stage hist in LDS, 8 parallel per-expert prefix scans,
// parallel writeback.
__global__ void k_offsets(const int* __restrict__ blockhist, int* __restrict__ pseg,
                          int* __restrict__ rcnt, int* __restrict__ blockbase) {
  __shared__ int h[64 * NEXP];
  __shared__ int tot[NEXP], ps[NEXP + 1];
  int t = threadIdx.x;  // 64 threads
#pragma unroll
  for (int j = 0; j < 8; j++) h[j * 64 + t] = blockhist[j * 64 + t];
  __syncthreads();
  if (t < NEXP) {
    int s = 0;
    for (int b = 0; b < 64; b++) {
      int v = h[b * NEXP + t];
      h[b * NEXP + t] = s;  // exclusive prefix within expert
      s += v;
    }
    tot[t] = s;
    rcnt[t] = s;
  }
  __syncthreads();
  if (t == 0) {
    int s = 0;
    for (int e = 0; e < NEXP; e++) { ps[e] = s; s += (tot[e] + 127) & ~127; }
    ps[NEXP] = s;
#pragma unroll
    for (int e = 0; e <= NEXP; e++) pseg[e] = ps[e];
  }
  __syncthreads();
#pragma unroll
  for (int j = 0; j < 8; j++) {
    int idx = j * 64 + t;  // idx = b*NEXP + e
    blockbase[idx] = h[idx] + ps[idx & 7];
  }
}

// Pass 3: scatter with per-block LDS cursors (no global atomics).
__global__ void k_scatter(const int* __restrict__ topi, const float* __restrict__ topw,
                          const int* __restrict__ blockbase,
                          int* __restrict__ ptok, float* __restrict__ pw) {
  __shared__ int cur[NEXP];
  if (threadIdx.x < NEXP) cur[threadIdx.x] = blockbase[blockIdx.x * NEXP + threadIdx.x];
  __syncthreads();
  int i = blockIdx.x * 256 + threadIdx.x;  // pair index
  int e = topi[i];
  int pos = atomicAdd(&cur[e], 1);
  ptok[pos] = i >> 1;
  pw[pos] = topw[i];
}

// ---------------- GEMM kernels (MFMA bf16 16x16x32, XOR-swizzled LDS) ----------------

// Fused gate/up + SiLU, shared expert: 128x64 tile, dual-B accs, DEFAULT order.
__global__ __launch_bounds__(256, 4) void k_gu_shared(
    const unsigned short* __restrict__ Xb,   // [8192][1024]
    const unsigned short* __restrict__ BgT,  // [4096][1024]
    const unsigned short* __restrict__ BuT,  // [4096][1024]
    unsigned short* __restrict__ H)          // [8192][4096]
{
  const int tm0 = blockIdx.x * 128;
  const int tn0 = blockIdx.y * 64;

  __shared__ __align__(16) unsigned short As[128 * BK];
  __shared__ __align__(16) unsigned short Bgs[64 * BK];
  __shared__ __align__(16) unsigned short Bus[64 * BK];

  const int tid = threadIdx.x;
  const int wave = tid >> 6, lane = tid & 63;
  const int wm = wave & 1, wn = wave >> 1;
  const int quad = lane >> 4, l16 = lane & 15;
  const int srow = lane >> 3;                        // 8 lanes per 64-elem row
  const int scol = ((lane & 7) ^ srow) * 8;          // swizzled global col block

  floatx4 accg[4][2] = {};
  floatx4 accu[4][2] = {};

  for (int k0 = 0; k0 < DDIM; k0 += BK) {
#pragma unroll
    for (int s = 0; s < 4; s++) {
      int rb = (wave * 4 + s) * 8;
      gload16(Xb + (size_t)(tm0 + rb + srow) * DDIM + k0 + scol, As + rb * BK);
    }
#pragma unroll
    for (int s = 0; s < 2; s++) {
      int rb = (wave * 2 + s) * 8;
      gload16(BgT + (size_t)(tn0 + rb + srow) * DDIM + k0 + scol, Bgs + rb * BK);
      gload16(BuT + (size_t)(tn0 + rb + srow) * DDIM + k0 + scol, Bus + rb * BK);
    }
    __syncthreads();
#pragma unroll
    for (int ks = 0; ks < BK; ks += 32) {
      short8 af[4], bg[2], bu[2];
#pragma unroll
      for (int f = 0; f < 4; f++) {
        int r = wm * 64 + f * 16 + l16;
        af[f] = *(const short8*)(As + r * BK + ((((ks >> 3) + quad) ^ (r & 7)) << 3));
      }
#pragma unroll
      for (int f = 0; f < 2; f++) {
        int r = wn * 32 + f * 16 + l16;
        int off = r * BK + ((((ks >> 3) + quad) ^ (r & 7)) << 3);
        bg[f] = *(const short8*)(Bgs + off);
        bu[f] = *(const short8*)(Bus + off);
      }
#pragma unroll
      for (int fm = 0; fm < 4; fm++)
#pragma unroll
        for (int fn = 0; fn < 2; fn++) {
          accg[fm][fn] = mfma16(af[fm], bg[fn], accg[fm][fn]);
          accu[fm][fn] = mfma16(af[fm], bu[fn], accu[fm][fn]);
        }
    }
    __syncthreads();
  }
#pragma unroll
  for (int fm = 0; fm < 4; fm++)
#pragma unroll
    for (int reg = 0; reg < 4; reg++) {
      int r = tm0 + wm * 64 + fm * 16 + quad * 4 + reg;
#pragma unroll
      for (int fn = 0; fn < 2; fn++) {
        int c = tn0 + wn * 32 + fn * 16 + l16;
        float g = accg[fm][fn][reg];
        float u = accu[fm][fn][reg];
        float h = (g / (1.f + __expf(-g))) * u;
        H[(size_t)r * ISH + c] = f2bf(h);
      }
    }
}

// Fused gate/up + SiLU for routed experts — A gathered on the fly from xb via
// per-lane ptok indirection. m-slab XCD swizzle (B 4MB/expert = L2-fit).
// MUST be launched 1-D with (PADTOT/128)*16 blocks.
__global__ __launch_bounds__(256, 4) void k_gu_expert(
    const unsigned short* __restrict__ Xb,   // [8192][1024]
    const unsigned short* __restrict__ EgT,  // [E][1024][1024]
    const unsigned short* __restrict__ EuT,
    const int* __restrict__ pseg,
    const int* __restrict__ ptok,
    unsigned short* __restrict__ Hp)         // [PADTOT][1024] by pair slot
{
  int bm, bn;
  swz_ms(blockIdx.x, PADTOT / 128, 16, bm, bn);
  const int m0 = bm * 128;
  if (m0 >= pseg[NEXP]) return;
  int e = 0;
#pragma unroll
  for (int j = 1; j < NEXP; j++) if (m0 >= pseg[j]) e = j;

  __shared__ __align__(16) unsigned short As[128 * BK];
  __shared__ __align__(16) unsigned short Bgs[64 * BK];
  __shared__ __align__(16) unsigned short Bus[64 * BK];

  const int tn0 = bn * 64;
  const int tid = threadIdx.x;
  const int wave = tid >> 6, lane = tid & 63;
  const int wm = wave & 1, wn = wave >> 1;
  const int quad = lane >> 4, l16 = lane & 15;
  const int srow = lane >> 3;
  const int scol = ((lane & 7) ^ srow) * 8;

  const unsigned short* Bg = EgT + (size_t)e * IMOE * DDIM;
  const unsigned short* Bu = EuT + (size_t)e * IMOE * DDIM;

  // indirect A staging pointers (4 parts of 32 rows each)
  const unsigned short* ArowP[4];
#pragma unroll
  for (int s = 0; s < 4; s++) {
    int tok = ptok[m0 + (wave * 4 + s) * 8 + srow];
    if (tok < 0 || tok >= T_TOK) tok = 0;  // pad slots: ptok is garbage
    ArowP[s] = Xb + (size_t)tok * DDIM + scol;
  }

  floatx4 accg[4][2] = {};
  floatx4 accu[4][2] = {};

  for (int k0 = 0; k0 < DDIM; k0 += BK) {
#pragma unroll
    for (int s = 0; s < 4; s++) {
      int rb = (wave * 4 + s) * 8;
      gload16(ArowP[s] + k0, As + rb * BK);
    }
#pragma unroll
    for (int s = 0; s < 2; s++) {
      int rb = (wave * 2 + s) * 8;
      gload16(Bg + (size_t)(tn0 + rb + srow) * DDIM + k0 + scol, Bgs + rb * BK);
      gload16(Bu + (size_t)(tn0 + rb + srow) * DDIM + k0 + scol, Bus + rb * BK);
    }
    __syncthreads();
#pragma unroll
    for (int ks = 0; ks < BK; ks += 32) {
      short8 af[4], bg[2], bu[2];
#pragma unroll
      for (int f = 0; f < 4; f++) {
        int r = wm * 64 + f * 16 + l16;
        af[f] = *(const short8*)(As + r * BK + ((((ks >> 3) + quad) ^ (r & 7)) << 3));
      }
#pragma unroll
      for (int f = 0; f < 2; f++) {
        int r = wn * 32 + f * 16 + l16;
        int off = r * BK + ((((ks >> 3) + quad) ^ (r & 7)) << 3);
        bg[f] = *(const short8*)(Bgs + off);
        bu[f] = *(const short8*)(Bus + off);
      }
#pragma unroll
      for (int fm = 0; fm < 4; fm++)
#pragma unroll
        for (int fn = 0; fn < 2; fn++) {
          accg[fm][fn] = mfma16(af[fm], bg[fn], accg[fm][fn]);
          accu[fm][fn] = mfma16(af[fm], bu[fn], accu[fm][fn]);
        }
    }
    __syncthreads();
  }
#pragma unroll
  for (int fm = 0; fm < 4; fm++)
#pragma unroll
    for (int reg = 0; reg < 4; reg++) {
      int r = m0 + wm * 64 + fm * 16 + quad * 4 + reg;
#pragma unroll
      for (int fn = 0; fn < 2; fn++) {
        int c = tn0 + wn * 32 + fn * 16 + l16;
        float g = accg[fm][fn][reg];
        float u = accu[fm][fn][reg];
        Hp[(size_t)r * IMOE + c] = f2bf((g / (1.f + __expf(-g))) * u);
      }
    }
}

// Shared-expert down proj: out = sigmoid_gate[t] * (Hsh @ sd). 128x128, DEFAULT.
__global__ __launch_bounds__(256, 4) void k_down_shared(
    const unsigned short* __restrict__ Hsh,  // [8192][4096]
    const unsigned short* __restrict__ SdT,  // [1024][4096]
    const float* __restrict__ sgate,
    float* __restrict__ out)                 // [8192][1024]
{
  __shared__ __align__(16) unsigned short As[128 * BK];
  __shared__ __align__(16) unsigned short Bs[128 * BK];

  const int tm0 = blockIdx.x * 128;
  const int tn0 = blockIdx.y * 128;
  const int tid = threadIdx.x;
  const int wave = tid >> 6, lane = tid & 63;
  const int wm = wave & 1, wn = wave >> 1;
  const int quad = lane >> 4, l16 = lane & 15;
  const int srow = lane >> 3;
  const int scol = ((lane & 7) ^ srow) * 8;

  floatx4 acc[4][4] = {};

  for (int k0 = 0; k0 < ISH; k0 += BK) {
#pragma unroll
    for (int s = 0; s < 4; s++) {
      int rb = (wave * 4 + s) * 8;
      gload16(Hsh + (size_t)(tm0 + rb + srow) * ISH + k0 + scol, As + rb * BK);
      gload16(SdT + (size_t)(tn0 + rb + srow) * ISH + k0 + scol, Bs + rb * BK);
    }
    __syncthreads();
#pragma unroll
    for (int ks = 0; ks < BK; ks += 32) {
      short8 af[4], bfr[4];
#pragma unroll
      for (int f = 0; f < 4; f++) {
        int ra = wm * 64 + f * 16 + l16;
        int rb2 = wn * 64 + f * 16 + l16;
        af[f] = *(const short8*)(As + ra * BK + ((((ks >> 3) + quad) ^ (ra & 7)) << 3));
        bfr[f] = *(const short8*)(Bs + rb2 * BK + ((((ks >> 3) + quad) ^ (rb2 & 7)) << 3));
      }
#pragma unroll
      for (int fm = 0; fm < 4; fm++)
#pragma unroll
        for (int fn = 0; fn < 4; fn++)
          acc[fm][fn] = mfma16(af[fm], bfr[fn], acc[fm][fn]);
    }
    __syncthreads();
  }
#pragma unroll
  for (int fm = 0; fm < 4; fm++)
#pragma unroll
    for (int reg = 0; reg < 4; reg++) {
      int r = tm0 + wm * 64 + fm * 16 + quad * 4 + reg;
      float gt = sgate[r];
#pragma unroll
      for (int fn = 0; fn < 4; fn++) {
        int c = tn0 + wn * 64 + fn * 16 + l16;
        out[(size_t)r * DDIM + c] = gt * acc[fm][fn][reg];
      }
    }
}

// Expert down proj: out[tok] += w_pair * (Hp @ ed[e]). 128x128, m-slab swizzle
// (B 2MB/expert = L2-fit). MUST be launched 1-D with (PADTOT/128)*8 blocks.
__global__ __launch_bounds__(256, 4) void k_down_expert(
    const unsigned short* __restrict__ Hp,   // [PADTOT][1024]
    const unsigned short* __restrict__ EdT,  // [E][1024][1024]
    const int* __restrict__ pseg,
    const int* __restrict__ rcnt,
    const int* __restrict__ ptok,
    const float* __restrict__ pw,
    float* __restrict__ out)
{
  int bm, bn;
  swz_ms(blockIdx.x, PADTOT / 128, 8, bm, bn);
  const int m0 = bm * 128;
  if (m0 >= pseg[NEXP]) return;
  int e = 0;
#pragma unroll
  for (int j = 1; j < NEXP; j++) if (m0 >= pseg[j]) e = j;
  const int sbase = pseg[e];
  const int cnt = rcnt[e];

  __shared__ __align__(16) unsigned short As[128 * BK];
  __shared__ __align__(16) unsigned short Bs[128 * BK];

  const int tn0 = bn * 128;
  const int tid = threadIdx.x;
  const int wave = tid >> 6, lane = tid & 63;
  const int wm = wave & 1, wn = wave >> 1;
  const int quad = lane >> 4, l16 = lane & 15;
  const int srow = lane >> 3;
  const int scol = ((lane & 7) ^ srow) * 8;

  const unsigned short* B = EdT + (size_t)e * IMOE * DDIM;

  floatx4 acc[4][4] = {};

  for (int k0 = 0; k0 < IMOE; k0 += BK) {
#pragma unroll
    for (int s = 0; s < 4; s++) {
      int rb = (wave * 4 + s) * 8;
      gload16(Hp + (size_t)(m0 + rb + srow) * IMOE + k0 + scol, As + rb * BK);
      gload16(B + (size_t)(tn0 + rb + srow) * IMOE + k0 + scol, Bs + rb * BK);
    }
    __syncthreads();
#pragma unroll
    for (int ks = 0; ks < BK; ks += 32) {
      short8 af[4], bfr[4];
#pragma unroll
      for (int f = 0; f < 4; f++) {
        int ra = wm * 64 + f * 16 + l16;
        int rb2 = wn * 64 + f * 16 + l16;
        af[f] = *(const short8*)(As + ra * BK + ((((ks >> 3) + quad) ^ (ra & 7)) << 3));
        bfr[f] = *(const short8*)(Bs + rb2 * BK + ((((ks >> 3) + quad) ^ (rb2 & 7)) << 3));
      }
#pragma unroll
      for (int fm = 0; fm < 4; fm++)
#pragma unroll
        for (int fn = 0; fn < 4; fn++)
          acc[fm][fn] = mfma16(af[fm], bfr[fn], acc[fm][fn]);
    }
    __syncthreads();
  }
#pragma unroll
  for (int fm = 0; fm < 4; fm++)
#pragma unroll
    for (int reg = 0; reg < 4; reg++) {
      int grow = m0 + wm * 64 + fm * 16 + quad * 4 + reg;
      if (grow - sbase < cnt) {
        int t = ptok[grow];
        float w = pw[grow];
#pragma unroll
        for (int fn = 0; fn < 4; fn++) {
          int c = tn0 + wn * 64 + fn * 16 + l16;
          atomicAdd(&out[(size_t)t * DDIM + c], w * acc[fm][fn][reg]);
        }
      }
    }
}

// ---------------- launch ----------------

extern "C" void kernel_launch(void* const* d_in, const int* in_sizes, int n_in,
                              void* d_out, int out_size, void* d_ws, size_t ws_size,
                              hipStream_t stream) {
  const float* x   = (const float*)d_in[0];
  const float* gw  = (const float*)d_in[1];
  const float* eg  = (const float*)d_in[2];
  const float* eu  = (const float*)d_in[3];
  const float* ed  = (const float*)d_in[4];
  const float* sg  = (const float*)d_in[5];
  const float* su  = (const float*)d_in[6];
  const float* sd  = (const float*)d_in[7];
  const float* sgw = (const float*)d_in[8];

  float* out    = (float*)d_out;                 // [8192][1024]
  float* logits = out + (size_t)T_TOK * DDIM;    // [8192][8]

  char* ws = (char*)d_ws;
  unsigned short* xb   = (unsigned short*)(ws + 0);            // 16 MB
  unsigned short* egT  = (unsigned short*)(ws + 16777216);     // 16 MB
  unsigned short* euT  = (unsigned short*)(ws + 33554432);     // 16 MB
  unsigned short* edT  = (unsigned short*)(ws + 50331648);     // 16 MB
  unsigned short* sgT  = (unsigned short*)(ws + 67108864);     // 8 MB
  unsigned short* suT  = (unsigned short*)(ws + 75497472);     // 8 MB
  unsigned short* sdT  = (unsigned short*)(ws + 83886080);     // 8 MB
  unsigned short* hsh  = (unsigned short*)(ws + 92274688);     // 64 MB
  unsigned short* hp   = (unsigned short*)(ws + 159383552);    // 35.65 MB
  int*   topi      = (int*)  (ws + 195035136);   // 16384 ints
  float* topw      = (float*)(ws + 195100672);   // 16384 floats
  float* sgate     = (float*)(ws + 195166208);   // 8192 floats
  int*   ptok      = (int*)  (ws + 195198976);   // PADTOT ints
  float* pw        = (float*)(ws + 195268608);   // PADTOT floats
  int*   blockhist = (int*)  (ws + 195338240);   // 64*8 ints
  int*   blockbase = (int*)  (ws + 195340288);   // 64*8 ints
  int*   pseg      = (int*)  (ws + 195342336);   // 9 ints
  int*   rcnt     = (int*)  (ws + 195342400);   // 8 ints

  k_router<<<T_TOK / 4, 256, 0, stream>>>(x, gw, sgw, logits, topi, topw, sgate, xb);
  k_tr_experts<<<dim3(16, 16, 24), 256, 0, stream>>>(eg, eu, ed, egT, euT, edT);
  k_tr_su<<<dim3(64, 16, 2), 256, 0, stream>>>(sg, su, sgT, suT);
  k_tr_sd<<<dim3(16, 64, 1), 256, 0, stream>>>(sd, sdT);

  k_hist<<<64, 256, 0, stream>>>(topi, blockhist);
  k_offsets<<<1, 64, 0, stream>>>(blockhist, pseg, rcnt, blockbase);
  k_scatter<<<64, 256, 0, stream>>>(topi, topw, blockbase, ptok, pw);

  // Producer->consumer adjacency; down_shared's plain stores complete (stream
  // order) before down_expert's atomics accumulate on top.
  // Expert kernels: 1-D grids — swz_ms decodes (m,n) from the single block id.
  k_gu_shared<<<dim3(64, 64), 256, 0, stream>>>(xb, sgT, suT, hsh);
  k_down_shared<<<dim3(64, 8), 256, 0, stream>>>(hsh, sdT, sgate, out);
  k_gu_expert<<<(PADTOT / 128) * 16, 256, 0, stream>>>(xb, egT, euT, pseg, ptok, hp);
  k_down_expert<<<(PADTOT / 128) * 8, 256, 0, stream>>>(hp, edT, pseg, rcnt, ptok, pw, out);

  (void)in_sizes; (void)n_in; (void)out_size; (void)ws_size;
}